// Round 7
// baseline (163.064 us; speedup 1.0000x reference)
//
#include <hip/hip_runtime.h>
#include <hip/hip_bf16.h>

#define BATCH 8
#define SEQ 4096
#define EMB 1024
#define HEAD 64
#define N3 192      // 3*HEAD: k | q | v
#define KQ_STR 128  // dense K|Q row stride

#define BM 64       // qkv block rows
#define BK 64       // qkv K-step
#define NT (EMB / BK)
#define LSTR 72     // padded LDS row stride in ushorts (64 + 8): 144B = 9*16B

typedef __attribute__((ext_vector_type(4))) float f32x4;
typedef __attribute__((ext_vector_type(8))) short bf16x8;
typedef __attribute__((ext_vector_type(4))) short short4v;
typedef __attribute__((ext_vector_type(4))) float float4v;
typedef __attribute__((ext_vector_type(4))) unsigned int u32x4;

#define LOG2E 1.4426950408889634f

static __device__ __forceinline__ unsigned short f2bf(float f) {
  unsigned int x = __builtin_bit_cast(unsigned int, f);
  x += 0x7fffu + ((x >> 16) & 1u);   // RTNE
  return (unsigned short)(x >> 16);
}

// --- Kernel 1: W [1024][192] f32 -> Wt [192][1024] bf16 ---
__global__ __launch_bounds__(256) void wt_kernel(const float* __restrict__ W,
                                                 unsigned short* __restrict__ Wt) {
  int idx = blockIdx.x * 256 + threadIdx.x;
  int k = idx / N3, c = idx % N3;
  Wt[(size_t)c * EMB + k] = f2bf(W[idx]);
}

// --- Kernel 2: canonical LDS-staged GEMM. 512 blocks x 256 thr (4 waves). ---
__global__ __launch_bounds__(256, 2) void qkv_kernel(const float* __restrict__ x,
                                                     const unsigned short* __restrict__ Wt,
                                                     unsigned short* __restrict__ kq,
                                                     unsigned short* __restrict__ Vt) {
  __shared__ unsigned short Asm[2][BM][LSTR];    // 2 x 64 x 144B = 18.4 KB
  __shared__ unsigned short Bsm[2][N3][LSTR];    // 2 x 192 x 144B = 55.3 KB

  const int tid = threadIdx.x;
  const int wid = tid >> 6;
  const int lane = tid & 63;
  const int l16 = lane & 15;
  const int lg = lane >> 4;
  const int m0 = blockIdx.x * BM;

  const int ar0 = tid >> 4;        // A row base: +16*i, i<4
  const int ac4 = tid & 15;        // A float4-chunk in row
  const int br0 = tid >> 3;        // B row base: +32*i, i<6
  const int bc = tid & 7;          // B bf16x8-chunk in row

  const float* xa = x + (size_t)(m0 + ar0) * EMB + ac4 * 4;
  const unsigned short* wb = Wt + (size_t)br0 * EMB + bc * 8;

  f32x4 acc[4][3];
#pragma unroll
  for (int mi = 0; mi < 4; ++mi)
#pragma unroll
    for (int ni = 0; ni < 3; ++ni) acc[mi][ni] = (f32x4)0.0f;

  float4v av[4];
  bf16x8 bv[6];

#define ISSUE_LOADS(K0)                                                        \
  {                                                                            \
    _Pragma("unroll") for (int i = 0; i < 4; ++i)                              \
        av[i] = *(const float4v*)(xa + (size_t)(16 * i) * EMB + (K0));         \
    _Pragma("unroll") for (int i = 0; i < 6; ++i)                              \
        bv[i] = *(const bf16x8*)(wb + (size_t)(32 * i) * EMB + (K0));          \
  }

#define WRITE_LDS(BUF)                                                         \
  {                                                                            \
    _Pragma("unroll") for (int i = 0; i < 4; ++i) {                            \
      short4v p;                                                               \
      _Pragma("unroll") for (int j = 0; j < 4; ++j)                            \
          p[j] = (short)f2bf(av[i][j]);                                        \
      *(short4v*)&Asm[BUF][ar0 + 16 * i][ac4 * 4] = p;                         \
    }                                                                          \
    _Pragma("unroll") for (int i = 0; i < 6; ++i)                              \
        *(bf16x8*)&Bsm[BUF][br0 + 32 * i][bc * 8] = bv[i];                     \
  }

#define COMPUTE(BUF)                                                           \
  {                                                                            \
    _Pragma("unroll") for (int kh = 0; kh < 2; ++kh) {                         \
      bf16x8 af[4], bfr[3];                                                    \
      _Pragma("unroll") for (int mi = 0; mi < 4; ++mi)                         \
          af[mi] = *(const bf16x8*)&Asm[BUF][mi * 16 + l16][kh * 32 + lg * 8]; \
      _Pragma("unroll") for (int ni = 0; ni < 3; ++ni)                         \
          bfr[ni] = *(const bf16x8*)&Bsm[BUF][wid * 48 + ni * 16 + l16][kh * 32 + lg * 8]; \
      _Pragma("unroll") for (int mi = 0; mi < 4; ++mi)                         \
        _Pragma("unroll") for (int ni = 0; ni < 3; ++ni)                       \
            acc[mi][ni] = __builtin_amdgcn_mfma_f32_16x16x32_bf16(             \
                af[mi], bfr[ni], acc[mi][ni], 0, 0, 0);                        \
    }                                                                          \
  }

  ISSUE_LOADS(0)
  WRITE_LDS(0)
  __syncthreads();

  int cur = 0;
  for (int t = 0; t < NT; ++t) {
    if (t < NT - 1) ISSUE_LOADS((t + 1) * BK)
    COMPUTE(cur)
    if (t < NT - 1) {
      WRITE_LDS(cur ^ 1)
    }
    __syncthreads();
    cur ^= 1;
  }
#undef ISSUE_LOADS
#undef WRITE_LDS
#undef COMPUTE

#pragma unroll
  for (int mi = 0; mi < 4; ++mi) {
#pragma unroll
    for (int ni = 0; ni < 3; ++ni) {
      const int n = wid * 48 + ni * 16 + l16;
#pragma unroll
      for (int r = 0; r < 4; ++r) {
        int row = m0 + mi * 16 + lg * 4 + r;
        float v = acc[mi][ni][r];
        if (n >= 64 && n < 128) v *= 0.125f;   // q pre-scale 1/sqrt(64)
        unsigned short h = f2bf(v);
        if (n < 128) {
          kq[(size_t)row * KQ_STR + n] = h;
        } else {
          int bb = row >> 12;
          int ss = row & (SEQ - 1);
          Vt[((size_t)bb * HEAD + (n - 128)) * SEQ + ss] = h;
        }
      }
    }
  }
}

// --- Kernel 3: causal flash attention, KV-split x4 within block, LSE merge ---
// 2048 blocks (one per 16-row q-chunk), 4 waves. Wave w handles KV-tile
// subrange [w*T/4, (w+1)*T/4); partials merged once via LDS.
__global__ __launch_bounds__(256) void attn_kernel(const unsigned short* __restrict__ kq,
                                                   const unsigned short* __restrict__ Vt,
                                                   float* __restrict__ out) {
  __shared__ float Msm[4][16];
  __shared__ float Lsm[4][16];
  __shared__ float Osm[4][4][16][17];   // [wave][dd][d-row][q] (+1 pad)

  const int tid = threadIdx.x;
  const int wid = tid >> 6;
  const int lane = tid & 63;
  const int l16 = lane & 15;
  const int lg = lane >> 4;

  const int Bid = blockIdx.x;
  const int b = Bid & 7;                    // batch (XCD-friendly spread)
  const int qc = 255 - (Bid >> 3);          // longest chunks first
  const int q0 = qc * 16;
  const int T_total = (q0 + 16 + 63) >> 6;  // tiles covering KV [0, q0+16)
  const int t0 = (wid * T_total) >> 2;
  const int t1 = ((wid + 1) * T_total) >> 2;

  const unsigned short* kqb = kq + (size_t)b * SEQ * KQ_STR;
  const unsigned short* vtb = Vt + (size_t)b * HEAD * SEQ;

  // Q fragments (B-operand of S^T mfma): col=l16 -> q row, k=lg*8+j -> d
  bf16x8 qf0 = *(const bf16x8*)(kqb + (size_t)(q0 + l16) * KQ_STR + 64 + lg * 8);
  bf16x8 qf1 = *(const bf16x8*)(kqb + (size_t)(q0 + l16) * KQ_STR + 96 + lg * 8);

  f32x4 o[4];
#pragma unroll
  for (int dd = 0; dd < 4; ++dd) o[dd] = (f32x4)0.0f;
  float m_ = -3.0e38f, lsum = 0.0f;

  if (t0 < t1) {
    // preload first K tile of this wave's range
    bf16x8 kf[8], kn[8];
#pragma unroll
    for (int t = 0; t < 4; ++t) {
      const unsigned short* kp = kqb + (size_t)((t0 << 6) + t * 16 + l16) * KQ_STR + lg * 8;
      kf[2 * t] = *(const bf16x8*)(kp);
      kf[2 * t + 1] = *(const bf16x8*)(kp + 32);
    }

    for (int it = t0; it < t1; ++it) {
      const int kv0 = it << 6;

      // prefetch next K tile within range (clamped)
      int nt_ = it + 1;
      if (nt_ > t1 - 1) nt_ = t1 - 1;
      const int kvn = nt_ << 6;
#pragma unroll
      for (int t = 0; t < 4; ++t) {
        const unsigned short* kp = kqb + (size_t)(kvn + t * 16 + l16) * KQ_STR + lg * 8;
        kn[2 * t] = *(const bf16x8*)(kp);
        kn[2 * t + 1] = *(const bf16x8*)(kp + 32);
      }
      // V fragments (A-operand of PV: row=l16 -> d, k -> kv)
      bf16x8 vf[8];
#pragma unroll
      for (int dd = 0; dd < 4; ++dd) {
        const unsigned short* vp = vtb + (size_t)(dd * 16 + l16) * SEQ + kv0 + lg * 8;
        vf[2 * dd] = *(const bf16x8*)(vp);
        vf[2 * dd + 1] = *(const bf16x8*)(vp + 32);
      }

      // S^T[kv][q]: lane holds kv = kv0+16t+lg*4+r for q = q0+l16
      f32x4 s[4];
#pragma unroll
      for (int t = 0; t < 4; ++t) {
        f32x4 z = (f32x4)0.0f;
        z = __builtin_amdgcn_mfma_f32_16x16x32_bf16(kf[2 * t], qf0, z, 0, 0, 0);
        z = __builtin_amdgcn_mfma_f32_16x16x32_bf16(kf[2 * t + 1], qf1, z, 0, 0, 0);
        s[t] = z;
      }

      // causal mask only on diagonal-crossing tiles (uniform branch)
      if (kv0 + 64 > q0) {
        const int base = kv0 + lg * 4 - q0 - l16;   // masked iff base + 16t + r > 0
#pragma unroll
        for (int t = 0; t < 4; ++t)
#pragma unroll
          for (int r = 0; r < 4; ++r)
            if (base + 16 * t + r > 0) s[t][r] = -3.0e38f;
      }

      // per-row max: 15 in-lane fmax + 2 shfl
      float mx = s[0][0];
#pragma unroll
      for (int t = 0; t < 4; ++t)
#pragma unroll
        for (int r = 0; r < 4; ++r)
          mx = fmaxf(mx, s[t][r]);
      mx = fmaxf(mx, __shfl_xor(mx, 16));
      mx = fmaxf(mx, __shfl_xor(mx, 32));

      // defer-max: rescale only when some row's max grew
      if (!__all(mx <= m_)) {
        float mn = fmaxf(m_, mx);
        float al = exp2f((m_ - mn) * LOG2E);
        m_ = mn;
        lsum *= al;
#pragma unroll
        for (int dd = 0; dd < 4; ++dd) o[dd] *= al;
      }

      // P = exp(S - m), pack to bf16 pairs, row-sum
      unsigned int pk[8];
      float ps = 0.0f;
#pragma unroll
      for (int t = 0; t < 4; ++t) {
        float p0 = exp2f((s[t][0] - m_) * LOG2E);
        float p1 = exp2f((s[t][1] - m_) * LOG2E);
        float p2 = exp2f((s[t][2] - m_) * LOG2E);
        float p3 = exp2f((s[t][3] - m_) * LOG2E);
        ps += (p0 + p1) + (p2 + p3);
        pk[2 * t] = (unsigned int)f2bf(p0) | ((unsigned int)f2bf(p1) << 16);
        pk[2 * t + 1] = (unsigned int)f2bf(p2) | ((unsigned int)f2bf(p3) << 16);
      }
      ps += __shfl_xor(ps, 16);
      ps += __shfl_xor(ps, 32);
      lsum += ps;

      // permute P into B-fragment layout: lane needs P[q=l16][kv=32c+lg*8+j]
      const int srcA = l16 + ((lg & 1) << 5);
      const int srcB = srcA + 16;
      const int hi = lg >> 1;
#pragma unroll
      for (int c = 0; c < 2; ++c) {
        unsigned int d0a = (unsigned int)__shfl((int)pk[4 * c], srcA);
        unsigned int d0b = (unsigned int)__shfl((int)pk[4 * c + 2], srcA);
        unsigned int d1a = (unsigned int)__shfl((int)pk[4 * c + 1], srcA);
        unsigned int d1b = (unsigned int)__shfl((int)pk[4 * c + 3], srcA);
        unsigned int d2a = (unsigned int)__shfl((int)pk[4 * c], srcB);
        unsigned int d2b = (unsigned int)__shfl((int)pk[4 * c + 2], srcB);
        unsigned int d3a = (unsigned int)__shfl((int)pk[4 * c + 1], srcB);
        unsigned int d3b = (unsigned int)__shfl((int)pk[4 * c + 3], srcB);
        u32x4 pw;
        pw[0] = hi ? d0b : d0a;
        pw[1] = hi ? d1b : d1a;
        pw[2] = hi ? d2b : d2a;
        pw[3] = hi ? d3b : d3a;
        bf16x8 pf = __builtin_bit_cast(bf16x8, pw);
#pragma unroll
        for (int dd = 0; dd < 4; ++dd)
          o[dd] = __builtin_amdgcn_mfma_f32_16x16x32_bf16(vf[2 * dd + c], pf, o[dd], 0, 0, 0);
      }

#pragma unroll
      for (int j = 0; j < 8; ++j) kf[j] = kn[j];
    }
  }

  // write partials to LDS
  if (lg == 0) {
    Msm[wid][l16] = m_;
    Lsm[wid][l16] = lsum;
  }
#pragma unroll
  for (int dd = 0; dd < 4; ++dd)
#pragma unroll
    for (int r = 0; r < 4; ++r)
      Osm[wid][dd][lg * 4 + r][l16] = o[dd][r];
  __syncthreads();

  // wave 0: LSE-merge the 4 partials and write out
  if (wid == 0) {
    float M = Msm[0][l16];
#pragma unroll
    for (int w = 1; w < 4; ++w) M = fmaxf(M, Msm[w][l16]);
    float L = 0.0f;
    f32x4 oc[4];
#pragma unroll
    for (int dd = 0; dd < 4; ++dd) oc[dd] = (f32x4)0.0f;
#pragma unroll
    for (int w = 0; w < 4; ++w) {
      float sc = exp2f((Msm[w][l16] - M) * LOG2E);
      L += Lsm[w][l16] * sc;
#pragma unroll
      for (int dd = 0; dd < 4; ++dd)
#pragma unroll
        for (int r = 0; r < 4; ++r)
          oc[dd][r] += Osm[w][dd][lg * 4 + r][l16] * sc;
    }
    const float inv = 1.0f / L;
    float* op = out + ((size_t)b * SEQ + q0 + l16) * HEAD;
#pragma unroll
    for (int dd = 0; dd < 4; ++dd)
#pragma unroll
      for (int r = 0; r < 4; ++r)
        op[16 * dd + lg * 4 + r] = oc[dd][r] * inv;
  }
}

extern "C" void kernel_launch(void* const* d_in, const int* in_sizes, int n_in,
                              void* d_out, int out_size, void* d_ws, size_t ws_size,
                              hipStream_t stream) {
  (void)in_sizes; (void)n_in; (void)out_size; (void)ws_size;
  const float* x = (const float*)d_in[0];
  const float* W = (const float*)d_in[1];
  float* out = (float*)d_out;

  unsigned short* Wt = (unsigned short*)d_ws;                                   // 384 KB
  unsigned short* kq = (unsigned short*)((char*)d_ws + 512 * 1024);             // 8 MB
  unsigned short* Vt = (unsigned short*)((char*)d_ws + 512 * 1024 + (size_t)BATCH * SEQ * KQ_STR * 2);  // 4 MB

  hipLaunchKernelGGL(wt_kernel, dim3((EMB * N3) / 256), dim3(256), 0, stream, W, Wt);
  hipLaunchKernelGGL(qkv_kernel, dim3((BATCH * SEQ) / BM), dim3(256), 0, stream, x, Wt, kq, Vt);
  hipLaunchKernelGGL(attn_kernel, dim3(BATCH * 256), dim3(256), 0, stream, kq, Vt, out);
}

// Round 8
// 156.046 us; speedup vs baseline: 1.0450x; 1.0450x over previous
//
#include <hip/hip_runtime.h>
#include <hip/hip_bf16.h>

#define BATCH 8
#define SEQ 4096
#define EMB 1024
#define HEAD 64
#define N3 192      // 3*HEAD: k | q | v
#define KQ_STR 128  // dense K|Q row stride

#define BM 64       // qkv block rows
#define BK 64       // qkv K-step
#define NT (EMB / BK)
#define LSTR 72     // padded LDS row stride in ushorts (64 + 8): 144B = 9*16B

typedef __attribute__((ext_vector_type(4))) float f32x4;
typedef __attribute__((ext_vector_type(8))) short bf16x8;
typedef __attribute__((ext_vector_type(4))) short short4v;
typedef __attribute__((ext_vector_type(4))) float float4v;
typedef __attribute__((ext_vector_type(4))) unsigned int u32x4;

#define LOG2E 1.4426950408889634f

static __device__ __forceinline__ unsigned short f2bf(float f) {
  unsigned int x = __builtin_bit_cast(unsigned int, f);
  x += 0x7fffu + ((x >> 16) & 1u);   // RTNE
  return (unsigned short)(x >> 16);
}

// --- Kernel 1: W [1024][192] f32 -> Wt [192][1024] bf16 ---
__global__ __launch_bounds__(256) void wt_kernel(const float* __restrict__ W,
                                                 unsigned short* __restrict__ Wt) {
  int idx = blockIdx.x * 256 + threadIdx.x;
  int k = idx / N3, c = idx % N3;
  Wt[(size_t)c * EMB + k] = f2bf(W[idx]);
}

// --- Kernel 2: canonical LDS-staged GEMM. 512 blocks x 256 thr (4 waves). ---
__global__ __launch_bounds__(256, 2) void qkv_kernel(const float* __restrict__ x,
                                                     const unsigned short* __restrict__ Wt,
                                                     unsigned short* __restrict__ kq,
                                                     unsigned short* __restrict__ Vt) {
  __shared__ unsigned short Asm[2][BM][LSTR];    // 2 x 64 x 144B = 18.4 KB
  __shared__ unsigned short Bsm[2][N3][LSTR];    // 2 x 192 x 144B = 55.3 KB

  const int tid = threadIdx.x;
  const int wid = tid >> 6;
  const int lane = tid & 63;
  const int l16 = lane & 15;
  const int lg = lane >> 4;
  const int m0 = blockIdx.x * BM;

  const int ar0 = tid >> 4;        // A row base: +16*i, i<4
  const int ac4 = tid & 15;        // A float4-chunk in row
  const int br0 = tid >> 3;        // B row base: +32*i, i<6
  const int bc = tid & 7;          // B bf16x8-chunk in row

  const float* xa = x + (size_t)(m0 + ar0) * EMB + ac4 * 4;
  const unsigned short* wb = Wt + (size_t)br0 * EMB + bc * 8;

  f32x4 acc[4][3];
#pragma unroll
  for (int mi = 0; mi < 4; ++mi)
#pragma unroll
    for (int ni = 0; ni < 3; ++ni) acc[mi][ni] = (f32x4)0.0f;

  float4v av[4];
  bf16x8 bv[6];

#define ISSUE_LOADS(K0)                                                        \
  {                                                                            \
    _Pragma("unroll") for (int i = 0; i < 4; ++i)                              \
        av[i] = *(const float4v*)(xa + (size_t)(16 * i) * EMB + (K0));         \
    _Pragma("unroll") for (int i = 0; i < 6; ++i)                              \
        bv[i] = *(const bf16x8*)(wb + (size_t)(32 * i) * EMB + (K0));          \
  }

#define WRITE_LDS(BUF)                                                         \
  {                                                                            \
    _Pragma("unroll") for (int i = 0; i < 4; ++i) {                            \
      short4v p;                                                               \
      _Pragma("unroll") for (int j = 0; j < 4; ++j)                            \
          p[j] = (short)f2bf(av[i][j]);                                        \
      *(short4v*)&Asm[BUF][ar0 + 16 * i][ac4 * 4] = p;                         \
    }                                                                          \
    _Pragma("unroll") for (int i = 0; i < 6; ++i)                              \
        *(bf16x8*)&Bsm[BUF][br0 + 32 * i][bc * 8] = bv[i];                     \
  }

#define COMPUTE(BUF)                                                           \
  {                                                                            \
    _Pragma("unroll") for (int kh = 0; kh < 2; ++kh) {                         \
      bf16x8 af[4], bfr[3];                                                    \
      _Pragma("unroll") for (int mi = 0; mi < 4; ++mi)                         \
          af[mi] = *(const bf16x8*)&Asm[BUF][mi * 16 + l16][kh * 32 + lg * 8]; \
      _Pragma("unroll") for (int ni = 0; ni < 3; ++ni)                         \
          bfr[ni] = *(const bf16x8*)&Bsm[BUF][wid * 48 + ni * 16 + l16][kh * 32 + lg * 8]; \
      _Pragma("unroll") for (int mi = 0; mi < 4; ++mi)                         \
        _Pragma("unroll") for (int ni = 0; ni < 3; ++ni)                       \
            acc[mi][ni] = __builtin_amdgcn_mfma_f32_16x16x32_bf16(             \
                af[mi], bfr[ni], acc[mi][ni], 0, 0, 0);                        \
    }                                                                          \
  }

  ISSUE_LOADS(0)
  WRITE_LDS(0)
  __syncthreads();

  int cur = 0;
  for (int t = 0; t < NT; ++t) {
    if (t < NT - 1) ISSUE_LOADS((t + 1) * BK)
    COMPUTE(cur)
    if (t < NT - 1) {
      WRITE_LDS(cur ^ 1)
    }
    __syncthreads();
    cur ^= 1;
  }
#undef ISSUE_LOADS
#undef WRITE_LDS
#undef COMPUTE

#pragma unroll
  for (int mi = 0; mi < 4; ++mi) {
#pragma unroll
    for (int ni = 0; ni < 3; ++ni) {
      const int n = wid * 48 + ni * 16 + l16;
#pragma unroll
      for (int r = 0; r < 4; ++r) {
        int row = m0 + mi * 16 + lg * 4 + r;
        float v = acc[mi][ni][r];
        if (n >= 64 && n < 128) v *= 0.125f;   // q pre-scale 1/sqrt(64)
        unsigned short h = f2bf(v);
        if (n < 128) {
          kq[(size_t)row * KQ_STR + n] = h;
        } else {
          int bb = row >> 12;
          int ss = row & (SEQ - 1);
          Vt[((size_t)bb * HEAD + (n - 128)) * SEQ + ss] = h;
        }
      }
    }
  }
}

// --- Kernel 3: causal flash attention, KV-split x4, LSE merge.
// __launch_bounds__(256,4): 128-VGPR budget so the 16 in-flight loads + acc
// stay live (76-VGPR default serialized the pipeline). K loaded at tile top
// (TLP-hidden), V issued after QK^T / consumed after softmax (T14).
__global__ __launch_bounds__(256, 4) void attn_kernel(const unsigned short* __restrict__ kq,
                                                      const unsigned short* __restrict__ Vt,
                                                      float* __restrict__ out) {
  __shared__ float Msm[4][16];
  __shared__ float Lsm[4][16];
  __shared__ float Osm[4][4][16][17];   // [wave][dd][d-row][q] (+1 pad)

  const int tid = threadIdx.x;
  const int wid = tid >> 6;
  const int lane = tid & 63;
  const int l16 = lane & 15;
  const int lg = lane >> 4;

  const int Bid = blockIdx.x;
  const int b = Bid & 7;                    // batch (XCD-friendly spread)
  const int qc = 255 - (Bid >> 3);          // longest chunks first
  const int q0 = qc * 16;
  const int T_total = (q0 + 16 + 63) >> 6;  // tiles covering KV [0, q0+16)
  const int t0 = (wid * T_total) >> 2;
  const int t1 = ((wid + 1) * T_total) >> 2;

  const unsigned short* kqb = kq + (size_t)b * SEQ * KQ_STR;
  const unsigned short* vtb = Vt + (size_t)b * HEAD * SEQ;

  // Q fragments (B-operand of S^T mfma): col=l16 -> q row, k=lg*8+j -> d
  bf16x8 qf0 = *(const bf16x8*)(kqb + (size_t)(q0 + l16) * KQ_STR + 64 + lg * 8);
  bf16x8 qf1 = *(const bf16x8*)(kqb + (size_t)(q0 + l16) * KQ_STR + 96 + lg * 8);

  f32x4 o[4];
#pragma unroll
  for (int dd = 0; dd < 4; ++dd) o[dd] = (f32x4)0.0f;
  float m_ = -3.0e38f, lsum = 0.0f;

  for (int it = t0; it < t1; ++it) {
    const int kv0 = it << 6;

    // K fragments for this tile (A-operand: row=l16 -> kv, k=lg*8+j -> d)
    bf16x8 kf[8];
#pragma unroll
    for (int t = 0; t < 4; ++t) {
      const unsigned short* kp = kqb + (size_t)(kv0 + t * 16 + l16) * KQ_STR + lg * 8;
      kf[2 * t] = *(const bf16x8*)(kp);
      kf[2 * t + 1] = *(const bf16x8*)(kp + 32);
    }

    // S^T[kv][q]: lane holds kv = kv0+16t+lg*4+r for q = q0+l16
    f32x4 s[4];
#pragma unroll
    for (int t = 0; t < 4; ++t) {
      f32x4 z = (f32x4)0.0f;
      z = __builtin_amdgcn_mfma_f32_16x16x32_bf16(kf[2 * t], qf0, z, 0, 0, 0);
      z = __builtin_amdgcn_mfma_f32_16x16x32_bf16(kf[2 * t + 1], qf1, z, 0, 0, 0);
      s[t] = z;
    }

    // V fragments issued here (kf dead); consumed after softmax (T14)
    bf16x8 vf[8];
#pragma unroll
    for (int dd = 0; dd < 4; ++dd) {
      const unsigned short* vp = vtb + (size_t)(dd * 16 + l16) * SEQ + kv0 + lg * 8;
      vf[2 * dd] = *(const bf16x8*)(vp);
      vf[2 * dd + 1] = *(const bf16x8*)(vp + 32);
    }

    // causal mask only on diagonal-crossing tiles (uniform branch)
    if (kv0 + 64 > q0) {
      const int base = kv0 + lg * 4 - q0 - l16;   // masked iff base + 16t + r > 0
#pragma unroll
      for (int t = 0; t < 4; ++t)
#pragma unroll
        for (int r = 0; r < 4; ++r)
          if (base + 16 * t + r > 0) s[t][r] = -3.0e38f;
    }

    // per-row max: 15 in-lane fmax + 2 shfl
    float mx = s[0][0];
#pragma unroll
    for (int t = 0; t < 4; ++t)
#pragma unroll
      for (int r = 0; r < 4; ++r)
        mx = fmaxf(mx, s[t][r]);
    mx = fmaxf(mx, __shfl_xor(mx, 16));
    mx = fmaxf(mx, __shfl_xor(mx, 32));

    // defer-max: rescale only when some row's max grew
    if (!__all(mx <= m_)) {
      float mn = fmaxf(m_, mx);
      float al = exp2f((m_ - mn) * LOG2E);
      m_ = mn;
      lsum *= al;
#pragma unroll
      for (int dd = 0; dd < 4; ++dd) o[dd] *= al;
    }

    // P = exp(S - m), pack to bf16 pairs, row-sum
    unsigned int pk[8];
    float ps = 0.0f;
#pragma unroll
    for (int t = 0; t < 4; ++t) {
      float p0 = exp2f((s[t][0] - m_) * LOG2E);
      float p1 = exp2f((s[t][1] - m_) * LOG2E);
      float p2 = exp2f((s[t][2] - m_) * LOG2E);
      float p3 = exp2f((s[t][3] - m_) * LOG2E);
      ps += (p0 + p1) + (p2 + p3);
      pk[2 * t] = (unsigned int)f2bf(p0) | ((unsigned int)f2bf(p1) << 16);
      pk[2 * t + 1] = (unsigned int)f2bf(p2) | ((unsigned int)f2bf(p3) << 16);
    }
    ps += __shfl_xor(ps, 16);
    ps += __shfl_xor(ps, 32);
    lsum += ps;

    // permute P into B-fragment layout: lane needs P[q=l16][kv=32c+lg*8+j]
    const int srcA = l16 + ((lg & 1) << 5);
    const int srcB = srcA + 16;
    const int hi = lg >> 1;
#pragma unroll
    for (int c = 0; c < 2; ++c) {
      unsigned int d0a = (unsigned int)__shfl((int)pk[4 * c], srcA);
      unsigned int d0b = (unsigned int)__shfl((int)pk[4 * c + 2], srcA);
      unsigned int d1a = (unsigned int)__shfl((int)pk[4 * c + 1], srcA);
      unsigned int d1b = (unsigned int)__shfl((int)pk[4 * c + 3], srcA);
      unsigned int d2a = (unsigned int)__shfl((int)pk[4 * c], srcB);
      unsigned int d2b = (unsigned int)__shfl((int)pk[4 * c + 2], srcB);
      unsigned int d3a = (unsigned int)__shfl((int)pk[4 * c + 1], srcB);
      unsigned int d3b = (unsigned int)__shfl((int)pk[4 * c + 3], srcB);
      u32x4 pw;
      pw[0] = hi ? d0b : d0a;
      pw[1] = hi ? d1b : d1a;
      pw[2] = hi ? d2b : d2a;
      pw[3] = hi ? d3b : d3a;
      bf16x8 pf = __builtin_bit_cast(bf16x8, pw);
#pragma unroll
      for (int dd = 0; dd < 4; ++dd)
        o[dd] = __builtin_amdgcn_mfma_f32_16x16x32_bf16(vf[2 * dd + c], pf, o[dd], 0, 0, 0);
    }
  }

  // write partials to LDS
  if (lg == 0) {
    Msm[wid][l16] = m_;
    Lsm[wid][l16] = lsum;
  }
#pragma unroll
  for (int dd = 0; dd < 4; ++dd)
#pragma unroll
    for (int r = 0; r < 4; ++r)
      Osm[wid][dd][lg * 4 + r][l16] = o[dd][r];
  __syncthreads();

  // wave 0: LSE-merge the 4 partials and write out
  if (wid == 0) {
    float M = Msm[0][l16];
#pragma unroll
    for (int w = 1; w < 4; ++w) M = fmaxf(M, Msm[w][l16]);
    float L = 0.0f;
    f32x4 oc[4];
#pragma unroll
    for (int dd = 0; dd < 4; ++dd) oc[dd] = (f32x4)0.0f;
#pragma unroll
    for (int w = 0; w < 4; ++w) {
      float sc = exp2f((Msm[w][l16] - M) * LOG2E);
      L += Lsm[w][l16] * sc;
#pragma unroll
      for (int dd = 0; dd < 4; ++dd)
#pragma unroll
        for (int r = 0; r < 4; ++r)
          oc[dd][r] += Osm[w][dd][lg * 4 + r][l16] * sc;
    }
    const float inv = 1.0f / L;
    float* op = out + ((size_t)b * SEQ + q0 + l16) * HEAD;
#pragma unroll
    for (int dd = 0; dd < 4; ++dd)
#pragma unroll
      for (int r = 0; r < 4; ++r)
        op[16 * dd + lg * 4 + r] = oc[dd][r] * inv;
  }
}

extern "C" void kernel_launch(void* const* d_in, const int* in_sizes, int n_in,
                              void* d_out, int out_size, void* d_ws, size_t ws_size,
                              hipStream_t stream) {
  (void)in_sizes; (void)n_in; (void)out_size; (void)ws_size;
  const float* x = (const float*)d_in[0];
  const float* W = (const float*)d_in[1];
  float* out = (float*)d_out;

  unsigned short* Wt = (unsigned short*)d_ws;                                   // 384 KB
  unsigned short* kq = (unsigned short*)((char*)d_ws + 512 * 1024);             // 8 MB
  unsigned short* Vt = (unsigned short*)((char*)d_ws + 512 * 1024 + (size_t)BATCH * SEQ * KQ_STR * 2);  // 4 MB

  hipLaunchKernelGGL(wt_kernel, dim3((EMB * N3) / 256), dim3(256), 0, stream, W, Wt);
  hipLaunchKernelGGL(qkv_kernel, dim3((BATCH * SEQ) / BM), dim3(256), 0, stream, x, Wt, kq, Vt);
  hipLaunchKernelGGL(attn_kernel, dim3(BATCH * 256), dim3(256), 0, stream, kq, Vt, out);
}

// Round 9
// 109.334 us; speedup vs baseline: 1.4914x; 1.4272x over previous
//
#include <hip/hip_runtime.h>
#include <hip/hip_bf16.h>

#define BATCH 8
#define SEQ 4096
#define EMB 1024
#define HEAD 64
#define N3 192      // 3*HEAD: k | q | v

#define BM 64       // qkv block rows
#define BK 64       // qkv K-step
#define NT (EMB / BK)
#define LSTR 72     // padded LDS row stride in ushorts (64 + 8): 144B = 9*16B

typedef __attribute__((ext_vector_type(4))) float f32x4;
typedef __attribute__((ext_vector_type(8))) short bf16x8;
typedef __attribute__((ext_vector_type(4))) short short4v;
typedef __attribute__((ext_vector_type(4))) float float4v;
typedef __attribute__((ext_vector_type(4))) unsigned int u32x4;

#define LOG2E 1.4426950408889634f

// Fragment-linear packing: each 1KB sub-tile holds a 16-row x 32-col bf16
// block, ordered so lane (l16,lg) reads its 16B MFMA fragment at
// subtile_base + (l16*4+lg)*16B  ->  one contiguous 1KB burst per wave-load.
// PK/PQ: [b][i=row/16][kh=d/32][512]   PV: [b][s=kv/64][dd=d/16][c=kv32][512]

static __device__ __forceinline__ unsigned short f2bf(float f) {
  unsigned int x = __builtin_bit_cast(unsigned int, f);
  x += 0x7fffu + ((x >> 16) & 1u);   // RTNE
  return (unsigned short)(x >> 16);
}

// --- Kernel 1: W [1024][192] f32 -> Wt [192][1024] bf16 ---
__global__ __launch_bounds__(256) void wt_kernel(const float* __restrict__ W,
                                                 unsigned short* __restrict__ Wt) {
  int idx = blockIdx.x * 256 + threadIdx.x;
  int k = idx / N3, c = idx % N3;
  Wt[(size_t)c * EMB + k] = f2bf(W[idx]);
}

// --- Kernel 2: canonical LDS-staged GEMM, epilogue packs fragment-linear ---
__global__ __launch_bounds__(256, 2) void qkv_kernel(const float* __restrict__ x,
                                                     const unsigned short* __restrict__ Wt,
                                                     unsigned short* __restrict__ PK,
                                                     unsigned short* __restrict__ PQ,
                                                     unsigned short* __restrict__ PV) {
  __shared__ unsigned short Asm[2][BM][LSTR];    // 2 x 64 x 144B = 18.4 KB
  __shared__ unsigned short Bsm[2][N3][LSTR];    // 2 x 192 x 144B = 55.3 KB

  const int tid = threadIdx.x;
  const int wid = tid >> 6;
  const int lane = tid & 63;
  const int l16 = lane & 15;
  const int lg = lane >> 4;
  const int m0 = blockIdx.x * BM;

  const int ar0 = tid >> 4;        // A row base: +16*i, i<4
  const int ac4 = tid & 15;        // A float4-chunk in row
  const int br0 = tid >> 3;        // B row base: +32*i, i<6
  const int bc = tid & 7;          // B bf16x8-chunk in row

  const float* xa = x + (size_t)(m0 + ar0) * EMB + ac4 * 4;
  const unsigned short* wb = Wt + (size_t)br0 * EMB + bc * 8;

  f32x4 acc[4][3];
#pragma unroll
  for (int mi = 0; mi < 4; ++mi)
#pragma unroll
    for (int ni = 0; ni < 3; ++ni) acc[mi][ni] = (f32x4)0.0f;

  float4v av[4];
  bf16x8 bv[6];

#define ISSUE_LOADS(K0)                                                        \
  {                                                                            \
    _Pragma("unroll") for (int i = 0; i < 4; ++i)                              \
        av[i] = *(const float4v*)(xa + (size_t)(16 * i) * EMB + (K0));         \
    _Pragma("unroll") for (int i = 0; i < 6; ++i)                              \
        bv[i] = *(const bf16x8*)(wb + (size_t)(32 * i) * EMB + (K0));          \
  }

#define WRITE_LDS(BUF)                                                         \
  {                                                                            \
    _Pragma("unroll") for (int i = 0; i < 4; ++i) {                            \
      short4v p;                                                               \
      _Pragma("unroll") for (int j = 0; j < 4; ++j)                            \
          p[j] = (short)f2bf(av[i][j]);                                        \
      *(short4v*)&Asm[BUF][ar0 + 16 * i][ac4 * 4] = p;                         \
    }                                                                          \
    _Pragma("unroll") for (int i = 0; i < 6; ++i)                              \
        *(bf16x8*)&Bsm[BUF][br0 + 32 * i][bc * 8] = bv[i];                     \
  }

#define COMPUTE(BUF)                                                           \
  {                                                                            \
    _Pragma("unroll") for (int kh = 0; kh < 2; ++kh) {                         \
      bf16x8 af[4], bfr[3];                                                    \
      _Pragma("unroll") for (int mi = 0; mi < 4; ++mi)                         \
          af[mi] = *(const bf16x8*)&Asm[BUF][mi * 16 + l16][kh * 32 + lg * 8]; \
      _Pragma("unroll") for (int ni = 0; ni < 3; ++ni)                         \
          bfr[ni] = *(const bf16x8*)&Bsm[BUF][wid * 48 + ni * 16 + l16][kh * 32 + lg * 8]; \
      _Pragma("unroll") for (int mi = 0; mi < 4; ++mi)                         \
        _Pragma("unroll") for (int ni = 0; ni < 3; ++ni)                       \
            acc[mi][ni] = __builtin_amdgcn_mfma_f32_16x16x32_bf16(             \
                af[mi], bfr[ni], acc[mi][ni], 0, 0, 0);                        \
    }                                                                          \
  }

  ISSUE_LOADS(0)
  WRITE_LDS(0)
  __syncthreads();

  int cur = 0;
  for (int t = 0; t < NT; ++t) {
    if (t < NT - 1) ISSUE_LOADS((t + 1) * BK)
    COMPUTE(cur)
    if (t < NT - 1) {
      WRITE_LDS(cur ^ 1)
    }
    __syncthreads();
    cur ^= 1;
  }
#undef ISSUE_LOADS
#undef WRITE_LDS
#undef COMPUTE

  // epilogue: D col = n (l16-resident), row = m0 + mi*16 + lg*4 + r
#pragma unroll
  for (int mi = 0; mi < 4; ++mi) {
#pragma unroll
    for (int ni = 0; ni < 3; ++ni) {
      const int n = wid * 48 + ni * 16 + l16;
#pragma unroll
      for (int r = 0; r < 4; ++r) {
        const int row = m0 + mi * 16 + lg * 4 + r;
        const int bb = row >> 12;
        const int ss = row & (SEQ - 1);
        const float v = acc[mi][ni][r];
        if (n < 64) {            // K
          PK[(((size_t)bb * 256 + (ss >> 4)) * 2 + (n >> 5)) * 512 +
             (ss & 15) * 32 + (n & 31)] = f2bf(v);
        } else if (n < 128) {    // Q (pre-scaled 1/sqrt(64))
          const int d = n - 64;
          PQ[(((size_t)bb * 256 + (ss >> 4)) * 2 + (d >> 5)) * 512 +
             (ss & 15) * 32 + (d & 31)] = f2bf(v * 0.125f);
        } else {                 // V
          const int d = n - 128;
          PV[(((size_t)bb * 64 + (ss >> 6)) * 8 + (d >> 4) * 2 + ((ss >> 5) & 1)) * 512 +
             (d & 15) * 32 + (ss & 31)] = f2bf(v);
        }
      }
    }
  }
}

// --- Kernel 3: causal flash attention, KV-split x4, LSE merge.
// All operand loads are contiguous 1KB wave bursts from fragment-packed buffers.
__global__ __launch_bounds__(256, 4) void attn_kernel(const unsigned short* __restrict__ PK,
                                                      const unsigned short* __restrict__ PQ,
                                                      const unsigned short* __restrict__ PV,
                                                      float* __restrict__ out) {
  __shared__ float Msm[4][16];
  __shared__ float Lsm[4][16];
  __shared__ float Osm[4][4][16][17];   // [wave][dd][d-row][q] (+1 pad)

  const int tid = threadIdx.x;
  const int wid = tid >> 6;
  const int lane = tid & 63;
  const int l16 = lane & 15;
  const int lg = lane >> 4;
  const int lam = (l16 * 4 + lg) * 8;   // lane's ushort offset in a 1KB sub-tile

  const int Bid = blockIdx.x;
  const int b = Bid & 7;                    // batch (XCD-friendly spread)
  const int qc = 255 - (Bid >> 3);          // longest chunks first
  const int q0 = qc * 16;
  const int T_total = (q0 + 16 + 63) >> 6;  // tiles covering KV [0, q0+16)
  const int t0 = (wid * T_total) >> 2;
  const int t1 = ((wid + 1) * T_total) >> 2;

  const unsigned short* pkb = PK + (size_t)b * 256 * 1024;
  const unsigned short* pqb = PQ + (size_t)b * 256 * 1024;
  const unsigned short* pvb = PV + (size_t)b * 64 * 8 * 512;

  // Q fragments (B-operand of S^T mfma)
  bf16x8 qf0 = *(const bf16x8*)(pqb + ((size_t)qc * 2 + 0) * 512 + lam);
  bf16x8 qf1 = *(const bf16x8*)(pqb + ((size_t)qc * 2 + 1) * 512 + lam);

  f32x4 o[4];
#pragma unroll
  for (int dd = 0; dd < 4; ++dd) o[dd] = (f32x4)0.0f;
  float m_ = -3.0e38f, lsum = 0.0f;

  for (int it = t0; it < t1; ++it) {
    const int kv0 = it << 6;

    // K fragments: 8 consecutive 1KB bursts
    bf16x8 kf[8];
#pragma unroll
    for (int t = 0; t < 4; ++t) {
      const unsigned short* kp = pkb + ((size_t)(it * 4 + t) * 2) * 512 + lam;
      kf[2 * t] = *(const bf16x8*)(kp);
      kf[2 * t + 1] = *(const bf16x8*)(kp + 512);
    }

    // S^T[kv][q]: lane holds kv = kv0+16t+lg*4+r for q = q0+l16
    f32x4 s[4];
#pragma unroll
    for (int t = 0; t < 4; ++t) {
      f32x4 z = (f32x4)0.0f;
      z = __builtin_amdgcn_mfma_f32_16x16x32_bf16(kf[2 * t], qf0, z, 0, 0, 0);
      z = __builtin_amdgcn_mfma_f32_16x16x32_bf16(kf[2 * t + 1], qf1, z, 0, 0, 0);
      s[t] = z;
    }

    // V fragments issued here (kf dead); consumed after softmax (T14)
    bf16x8 vf[8];
#pragma unroll
    for (int dd = 0; dd < 4; ++dd) {
      const unsigned short* vp = pvb + ((size_t)it * 8 + dd * 2) * 512 + lam;
      vf[2 * dd] = *(const bf16x8*)(vp);
      vf[2 * dd + 1] = *(const bf16x8*)(vp + 512);
    }

    // causal mask only on diagonal-crossing tiles (uniform branch)
    if (kv0 + 64 > q0) {
      const int base = kv0 + lg * 4 - q0 - l16;   // masked iff base + 16t + r > 0
#pragma unroll
      for (int t = 0; t < 4; ++t)
#pragma unroll
        for (int r = 0; r < 4; ++r)
          if (base + 16 * t + r > 0) s[t][r] = -3.0e38f;
    }

    // per-row max: 15 in-lane fmax + 2 shfl
    float mx = s[0][0];
#pragma unroll
    for (int t = 0; t < 4; ++t)
#pragma unroll
      for (int r = 0; r < 4; ++r)
        mx = fmaxf(mx, s[t][r]);
    mx = fmaxf(mx, __shfl_xor(mx, 16));
    mx = fmaxf(mx, __shfl_xor(mx, 32));

    // defer-max: rescale only when some row's max grew
    if (!__all(mx <= m_)) {
      float mn = fmaxf(m_, mx);
      float al = exp2f((m_ - mn) * LOG2E);
      m_ = mn;
      lsum *= al;
#pragma unroll
      for (int dd = 0; dd < 4; ++dd) o[dd] *= al;
    }

    // P = exp(S - m), pack to bf16 pairs, row-sum
    unsigned int pk[8];
    float ps = 0.0f;
#pragma unroll
    for (int t = 0; t < 4; ++t) {
      float p0 = exp2f((s[t][0] - m_) * LOG2E);
      float p1 = exp2f((s[t][1] - m_) * LOG2E);
      float p2 = exp2f((s[t][2] - m_) * LOG2E);
      float p3 = exp2f((s[t][3] - m_) * LOG2E);
      ps += (p0 + p1) + (p2 + p3);
      pk[2 * t] = (unsigned int)f2bf(p0) | ((unsigned int)f2bf(p1) << 16);
      pk[2 * t + 1] = (unsigned int)f2bf(p2) | ((unsigned int)f2bf(p3) << 16);
    }
    ps += __shfl_xor(ps, 16);
    ps += __shfl_xor(ps, 32);
    lsum += ps;

    // permute P into B-fragment layout: lane needs P[q=l16][kv=32c+lg*8+j]
    const int srcA = l16 + ((lg & 1) << 5);
    const int srcB = srcA + 16;
    const int hi = lg >> 1;
#pragma unroll
    for (int c = 0; c < 2; ++c) {
      unsigned int d0a = (unsigned int)__shfl((int)pk[4 * c], srcA);
      unsigned int d0b = (unsigned int)__shfl((int)pk[4 * c + 2], srcA);
      unsigned int d1a = (unsigned int)__shfl((int)pk[4 * c + 1], srcA);
      unsigned int d1b = (unsigned int)__shfl((int)pk[4 * c + 3], srcA);
      unsigned int d2a = (unsigned int)__shfl((int)pk[4 * c], srcB);
      unsigned int d2b = (unsigned int)__shfl((int)pk[4 * c + 2], srcB);
      unsigned int d3a = (unsigned int)__shfl((int)pk[4 * c + 1], srcB);
      unsigned int d3b = (unsigned int)__shfl((int)pk[4 * c + 3], srcB);
      u32x4 pw;
      pw[0] = hi ? d0b : d0a;
      pw[1] = hi ? d1b : d1a;
      pw[2] = hi ? d2b : d2a;
      pw[3] = hi ? d3b : d3a;
      bf16x8 pf = __builtin_bit_cast(bf16x8, pw);
#pragma unroll
      for (int dd = 0; dd < 4; ++dd)
        o[dd] = __builtin_amdgcn_mfma_f32_16x16x32_bf16(vf[2 * dd + c], pf, o[dd], 0, 0, 0);
    }
  }

  // write partials to LDS
  if (lg == 0) {
    Msm[wid][l16] = m_;
    Lsm[wid][l16] = lsum;
  }
#pragma unroll
  for (int dd = 0; dd < 4; ++dd)
#pragma unroll
    for (int r = 0; r < 4; ++r)
      Osm[wid][dd][lg * 4 + r][l16] = o[dd][r];
  __syncthreads();

  // wave 0: LSE-merge the 4 partials and write out
  if (wid == 0) {
    float M = Msm[0][l16];
#pragma unroll
    for (int w = 1; w < 4; ++w) M = fmaxf(M, Msm[w][l16]);
    float L = 0.0f;
    f32x4 oc[4];
#pragma unroll
    for (int dd = 0; dd < 4; ++dd) oc[dd] = (f32x4)0.0f;
#pragma unroll
    for (int w = 0; w < 4; ++w) {
      float sc = exp2f((Msm[w][l16] - M) * LOG2E);
      L += Lsm[w][l16] * sc;
#pragma unroll
      for (int dd = 0; dd < 4; ++dd)
#pragma unroll
        for (int r = 0; r < 4; ++r)
          oc[dd][r] += Osm[w][dd][lg * 4 + r][l16] * sc;
    }
    const float inv = 1.0f / L;
    float* op = out + ((size_t)b * SEQ + q0 + l16) * HEAD;
#pragma unroll
    for (int dd = 0; dd < 4; ++dd)
#pragma unroll
      for (int r = 0; r < 4; ++r)
        op[16 * dd + lg * 4 + r] = oc[dd][r] * inv;
  }
}

extern "C" void kernel_launch(void* const* d_in, const int* in_sizes, int n_in,
                              void* d_out, int out_size, void* d_ws, size_t ws_size,
                              hipStream_t stream) {
  (void)in_sizes; (void)n_in; (void)out_size; (void)ws_size;
  const float* x = (const float*)d_in[0];
  const float* W = (const float*)d_in[1];
  float* out = (float*)d_out;

  const size_t MB4 = (size_t)4 * 1024 * 1024;
  unsigned short* Wt = (unsigned short*)d_ws;                               // 384 KB
  unsigned short* PK = (unsigned short*)((char*)d_ws + 512 * 1024);         // 4 MB
  unsigned short* PQ = (unsigned short*)((char*)d_ws + 512 * 1024 + MB4);   // 4 MB
  unsigned short* PV = (unsigned short*)((char*)d_ws + 512 * 1024 + 2 * MB4); // 4 MB

  hipLaunchKernelGGL(wt_kernel, dim3((EMB * N3) / 256), dim3(256), 0, stream, W, Wt);
  hipLaunchKernelGGL(qkv_kernel, dim3((BATCH * SEQ) / BM), dim3(256), 0, stream, x, Wt, PK, PQ, PV);
  hipLaunchKernelGGL(attn_kernel, dim3(BATCH * 256), dim3(256), 0, stream, PK, PQ, PV, out);
}

// Round 10
// 106.140 us; speedup vs baseline: 1.5363x; 1.0301x over previous
//
#include <hip/hip_runtime.h>
#include <hip/hip_bf16.h>

#define BATCH 8
#define SEQ 4096
#define EMB 1024
#define HEAD 64
#define N3 192      // 3*HEAD: k | q | v

#define BM 64       // qkv block rows
#define BK 64       // qkv K-step
#define NT (EMB / BK)
#define LSTR 72     // padded LDS row stride in ushorts (64 + 8): 144B = 9*16B

typedef __attribute__((ext_vector_type(4))) float f32x4;
typedef __attribute__((ext_vector_type(8))) short bf16x8;
typedef __attribute__((ext_vector_type(4))) short short4v;
typedef __attribute__((ext_vector_type(4))) float float4v;
typedef __attribute__((ext_vector_type(4))) unsigned int u32x4;

#define LOG2E 1.4426950408889634f
#define QSCALE (0.125f * LOG2E)   // 1/sqrt(64) folded with log2e: scores in log2 domain

// Fragment-linear packing: each 1KB sub-tile holds a 16-row x 32-col bf16
// block, ordered so lane (l16,lg) reads its 16B MFMA fragment at
// subtile_base + (l16*4+lg)*16B  ->  one contiguous 1KB burst per wave-load.
// PK/PQ: [b][i=row/16][kh=d/32][512]   PV: [b][s=kv/64][dd=d/16][c=kv32][512]

static __device__ __forceinline__ unsigned short f2bf(float f) {
  unsigned int x = __builtin_bit_cast(unsigned int, f);
  x += 0x7fffu + ((x >> 16) & 1u);   // RTNE
  return (unsigned short)(x >> 16);
}

// --- Kernel 1: W [1024][192] f32 -> Wt [192][1024] bf16 ---
__global__ __launch_bounds__(256) void wt_kernel(const float* __restrict__ W,
                                                 unsigned short* __restrict__ Wt) {
  int idx = blockIdx.x * 256 + threadIdx.x;
  int k = idx / N3, c = idx % N3;
  Wt[(size_t)c * EMB + k] = f2bf(W[idx]);
}

// --- Kernel 2: canonical LDS-staged GEMM, epilogue packs fragment-linear ---
__global__ __launch_bounds__(256, 2) void qkv_kernel(const float* __restrict__ x,
                                                     const unsigned short* __restrict__ Wt,
                                                     unsigned short* __restrict__ PK,
                                                     unsigned short* __restrict__ PQ,
                                                     unsigned short* __restrict__ PV) {
  __shared__ unsigned short Asm[2][BM][LSTR];    // 2 x 64 x 144B = 18.4 KB
  __shared__ unsigned short Bsm[2][N3][LSTR];    // 2 x 192 x 144B = 55.3 KB

  const int tid = threadIdx.x;
  const int wid = tid >> 6;
  const int lane = tid & 63;
  const int l16 = lane & 15;
  const int lg = lane >> 4;
  const int m0 = blockIdx.x * BM;

  const int ar0 = tid >> 4;        // A row base: +16*i, i<4
  const int ac4 = tid & 15;        // A float4-chunk in row
  const int br0 = tid >> 3;        // B row base: +32*i, i<6
  const int bc = tid & 7;          // B bf16x8-chunk in row

  const float* xa = x + (size_t)(m0 + ar0) * EMB + ac4 * 4;
  const unsigned short* wb = Wt + (size_t)br0 * EMB + bc * 8;

  f32x4 acc[4][3];
#pragma unroll
  for (int mi = 0; mi < 4; ++mi)
#pragma unroll
    for (int ni = 0; ni < 3; ++ni) acc[mi][ni] = (f32x4)0.0f;

  float4v av[4];
  bf16x8 bv[6];

#define ISSUE_LOADS(K0)                                                        \
  {                                                                            \
    _Pragma("unroll") for (int i = 0; i < 4; ++i)                              \
        av[i] = *(const float4v*)(xa + (size_t)(16 * i) * EMB + (K0));         \
    _Pragma("unroll") for (int i = 0; i < 6; ++i)                              \
        bv[i] = *(const bf16x8*)(wb + (size_t)(32 * i) * EMB + (K0));          \
  }

#define WRITE_LDS(BUF)                                                         \
  {                                                                            \
    _Pragma("unroll") for (int i = 0; i < 4; ++i) {                            \
      short4v p;                                                               \
      _Pragma("unroll") for (int j = 0; j < 4; ++j)                            \
          p[j] = (short)f2bf(av[i][j]);                                        \
      *(short4v*)&Asm[BUF][ar0 + 16 * i][ac4 * 4] = p;                         \
    }                                                                          \
    _Pragma("unroll") for (int i = 0; i < 6; ++i)                              \
        *(bf16x8*)&Bsm[BUF][br0 + 32 * i][bc * 8] = bv[i];                     \
  }

#define COMPUTE(BUF)                                                           \
  {                                                                            \
    _Pragma("unroll") for (int kh = 0; kh < 2; ++kh) {                         \
      bf16x8 af[4], bfr[3];                                                    \
      _Pragma("unroll") for (int mi = 0; mi < 4; ++mi)                         \
          af[mi] = *(const bf16x8*)&Asm[BUF][mi * 16 + l16][kh * 32 + lg * 8]; \
      _Pragma("unroll") for (int ni = 0; ni < 3; ++ni)                         \
          bfr[ni] = *(const bf16x8*)&Bsm[BUF][wid * 48 + ni * 16 + l16][kh * 32 + lg * 8]; \
      _Pragma("unroll") for (int mi = 0; mi < 4; ++mi)                         \
        _Pragma("unroll") for (int ni = 0; ni < 3; ++ni)                       \
            acc[mi][ni] = __builtin_amdgcn_mfma_f32_16x16x32_bf16(             \
                af[mi], bfr[ni], acc[mi][ni], 0, 0, 0);                        \
    }                                                                          \
  }

  ISSUE_LOADS(0)
  WRITE_LDS(0)
  __syncthreads();

  int cur = 0;
  for (int t = 0; t < NT; ++t) {
    if (t < NT - 1) ISSUE_LOADS((t + 1) * BK)
    COMPUTE(cur)
    if (t < NT - 1) {
      WRITE_LDS(cur ^ 1)
    }
    __syncthreads();
    cur ^= 1;
  }
#undef ISSUE_LOADS
#undef WRITE_LDS
#undef COMPUTE

  // epilogue: D col = n (l16-resident), row = m0 + mi*16 + lg*4 + r
#pragma unroll
  for (int mi = 0; mi < 4; ++mi) {
#pragma unroll
    for (int ni = 0; ni < 3; ++ni) {
      const int n = wid * 48 + ni * 16 + l16;
#pragma unroll
      for (int r = 0; r < 4; ++r) {
        const int row = m0 + mi * 16 + lg * 4 + r;
        const int bb = row >> 12;
        const int ss = row & (SEQ - 1);
        const float v = acc[mi][ni][r];
        if (n < 64) {            // K
          PK[(((size_t)bb * 256 + (ss >> 4)) * 2 + (n >> 5)) * 512 +
             (ss & 15) * 32 + (n & 31)] = f2bf(v);
        } else if (n < 128) {    // Q (pre-scaled 1/sqrt(64) * log2e)
          const int d = n - 64;
          PQ[(((size_t)bb * 256 + (ss >> 4)) * 2 + (d >> 5)) * 512 +
             (ss & 15) * 32 + (d & 31)] = f2bf(v * QSCALE);
        } else {                 // V
          const int d = n - 128;
          PV[(((size_t)bb * 64 + (ss >> 6)) * 8 + (d >> 4) * 2 + ((ss >> 5) & 1)) * 512 +
             (d & 15) * 32 + (ss & 31)] = f2bf(v);
        }
      }
    }
  }
}

// --- Kernel 3: causal flash attention. 1024 blocks, 4 waves. Each wave owns
// TWO consecutive 16-row q-chunks (shared K/V loads, 2 independent softmax
// chains for ILP) over its KV-split range; two-phase LSE merge.
__global__ __launch_bounds__(256, 4) void attn_kernel(const unsigned short* __restrict__ PK,
                                                      const unsigned short* __restrict__ PQ,
                                                      const unsigned short* __restrict__ PV,
                                                      float* __restrict__ out) {
  __shared__ float Msm[4][16];
  __shared__ float Lsm[4][16];
  __shared__ float Osm[4][4][16][17];   // [wave][dd][d-row][q] (+1 pad)

  const int tid = threadIdx.x;
  const int wid = tid >> 6;
  const int lane = tid & 63;
  const int l16 = lane & 15;
  const int lg = lane >> 4;
  const int lam = (l16 * 4 + lg) * 8;   // lane's ushort offset in a 1KB sub-tile

  const int Bid = blockIdx.x;
  const int b = Bid & 7;                    // batch (XCD-friendly spread)
  const int p = 127 - (Bid >> 3);           // pair index, longest first
  const int qc0 = 2 * p, qc1 = 2 * p + 1;
  const int q0a = qc0 * 16, q0b = qc1 * 16;
  const int T_total = (q0b + 16 + 63) >> 6; // tiles covering KV [0, q0b+16)
  const int t0 = (wid * T_total) >> 2;
  const int t1 = ((wid + 1) * T_total) >> 2;

  const unsigned short* pkb = PK + (size_t)b * 256 * 1024;
  const unsigned short* pqb = PQ + (size_t)b * 256 * 1024;
  const unsigned short* pvb = PV + (size_t)b * 64 * 8 * 512;

  // Q fragments for both chunks (B-operand of S^T mfma)
  bf16x8 qa0 = *(const bf16x8*)(pqb + ((size_t)qc0 * 2 + 0) * 512 + lam);
  bf16x8 qa1 = *(const bf16x8*)(pqb + ((size_t)qc0 * 2 + 1) * 512 + lam);
  bf16x8 qb0 = *(const bf16x8*)(pqb + ((size_t)qc1 * 2 + 0) * 512 + lam);
  bf16x8 qb1 = *(const bf16x8*)(pqb + ((size_t)qc1 * 2 + 1) * 512 + lam);

  f32x4 oA[4], oB[4];
#pragma unroll
  for (int dd = 0; dd < 4; ++dd) { oA[dd] = (f32x4)0.0f; oB[dd] = (f32x4)0.0f; }
  float mA = -3.0e38f, lA = 0.0f, mB = -3.0e38f, lB = 0.0f;

  const int srcA_ = l16 + ((lg & 1) << 5);
  const int srcB_ = srcA_ + 16;
  const int hi_ = lg >> 1;

  for (int it = t0; it < t1; ++it) {
    const int kv0 = it << 6;

    // QK^T for both chunks; kf transient (8 regs live)
    f32x4 s0[4], s1[4];
#pragma unroll
    for (int t = 0; t < 4; ++t) {
      const unsigned short* kp = pkb + ((size_t)(it * 4 + t) * 2) * 512 + lam;
      bf16x8 kfa = *(const bf16x8*)(kp);
      bf16x8 kfb = *(const bf16x8*)(kp + 512);
      f32x4 z = (f32x4)0.0f;
      z = __builtin_amdgcn_mfma_f32_16x16x32_bf16(kfa, qa0, z, 0, 0, 0);
      s0[t] = __builtin_amdgcn_mfma_f32_16x16x32_bf16(kfb, qa1, z, 0, 0, 0);
      z = (f32x4)0.0f;
      z = __builtin_amdgcn_mfma_f32_16x16x32_bf16(kfa, qb0, z, 0, 0, 0);
      s1[t] = __builtin_amdgcn_mfma_f32_16x16x32_bf16(kfb, qb1, z, 0, 0, 0);
    }

    // causal masks (uniform per chunk)
    if (kv0 + 64 > q0a) {
      const int base = kv0 + lg * 4 - q0a - l16;
#pragma unroll
      for (int t = 0; t < 4; ++t)
#pragma unroll
        for (int r = 0; r < 4; ++r)
          if (base + 16 * t + r > 0) s0[t][r] = -3.0e38f;
    }
    if (kv0 + 64 > q0b) {
      const int base = kv0 + lg * 4 - q0b - l16;
#pragma unroll
      for (int t = 0; t < 4; ++t)
#pragma unroll
        for (int r = 0; r < 4; ++r)
          if (base + 16 * t + r > 0) s1[t][r] = -3.0e38f;
    }

    // ---- chunk A softmax (log2 domain: P = exp2(s - m)) ----
    unsigned int pkA[8];
    {
      float mx = s0[0][0];
#pragma unroll
      for (int t = 0; t < 4; ++t)
#pragma unroll
        for (int r = 0; r < 4; ++r) mx = fmaxf(mx, s0[t][r]);
      mx = fmaxf(mx, __shfl_xor(mx, 16));
      mx = fmaxf(mx, __shfl_xor(mx, 32));
      if (!__all(mx <= mA)) {
        float mn = fmaxf(mA, mx);
        float al = exp2f(mA - mn);
        mA = mn; lA *= al;
#pragma unroll
        for (int dd = 0; dd < 4; ++dd) oA[dd] *= al;
      }
      float ps = 0.0f;
#pragma unroll
      for (int t = 0; t < 4; ++t) {
        float p0 = exp2f(s0[t][0] - mA);
        float p1 = exp2f(s0[t][1] - mA);
        float p2 = exp2f(s0[t][2] - mA);
        float p3 = exp2f(s0[t][3] - mA);
        ps += (p0 + p1) + (p2 + p3);
        pkA[2 * t] = (__builtin_bit_cast(unsigned int, p1) & 0xFFFF0000u) |
                     (__builtin_bit_cast(unsigned int, p0) >> 16);
        pkA[2 * t + 1] = (__builtin_bit_cast(unsigned int, p3) & 0xFFFF0000u) |
                         (__builtin_bit_cast(unsigned int, p2) >> 16);
      }
      ps += __shfl_xor(ps, 16);
      ps += __shfl_xor(ps, 32);
      lA += ps;
    }

    // V fragments (kf dead; consumed at PV)
    bf16x8 vf[8];
#pragma unroll
    for (int dd = 0; dd < 4; ++dd) {
      const unsigned short* vp = pvb + ((size_t)it * 8 + dd * 2) * 512 + lam;
      vf[2 * dd] = *(const bf16x8*)(vp);
      vf[2 * dd + 1] = *(const bf16x8*)(vp + 512);
    }

    // ---- chunk B softmax ----
    unsigned int pkB[8];
    {
      float mx = s1[0][0];
#pragma unroll
      for (int t = 0; t < 4; ++t)
#pragma unroll
        for (int r = 0; r < 4; ++r) mx = fmaxf(mx, s1[t][r]);
      mx = fmaxf(mx, __shfl_xor(mx, 16));
      mx = fmaxf(mx, __shfl_xor(mx, 32));
      if (!__all(mx <= mB)) {
        float mn = fmaxf(mB, mx);
        float al = exp2f(mB - mn);
        mB = mn; lB *= al;
#pragma unroll
        for (int dd = 0; dd < 4; ++dd) oB[dd] *= al;
      }
      float ps = 0.0f;
#pragma unroll
      for (int t = 0; t < 4; ++t) {
        float p0 = exp2f(s1[t][0] - mB);
        float p1 = exp2f(s1[t][1] - mB);
        float p2 = exp2f(s1[t][2] - mB);
        float p3 = exp2f(s1[t][3] - mB);
        ps += (p0 + p1) + (p2 + p3);
        pkB[2 * t] = (__builtin_bit_cast(unsigned int, p1) & 0xFFFF0000u) |
                     (__builtin_bit_cast(unsigned int, p0) >> 16);
        pkB[2 * t + 1] = (__builtin_bit_cast(unsigned int, p3) & 0xFFFF0000u) |
                         (__builtin_bit_cast(unsigned int, p2) >> 16);
      }
      ps += __shfl_xor(ps, 16);
      ps += __shfl_xor(ps, 32);
      lB += ps;
    }

    // ---- permute P into B-fragment layout + PV, per chunk ----
#define PERMUTE_PV(PKA, OACC)                                                  \
  {                                                                            \
    _Pragma("unroll") for (int c = 0; c < 2; ++c) {                            \
      unsigned int d0a = (unsigned int)__shfl((int)PKA[4 * c], srcA_);         \
      unsigned int d0b = (unsigned int)__shfl((int)PKA[4 * c + 2], srcA_);     \
      unsigned int d1a = (unsigned int)__shfl((int)PKA[4 * c + 1], srcA_);     \
      unsigned int d1b = (unsigned int)__shfl((int)PKA[4 * c + 3], srcA_);     \
      unsigned int d2a = (unsigned int)__shfl((int)PKA[4 * c], srcB_);         \
      unsigned int d2b = (unsigned int)__shfl((int)PKA[4 * c + 2], srcB_);     \
      unsigned int d3a = (unsigned int)__shfl((int)PKA[4 * c + 1], srcB_);     \
      unsigned int d3b = (unsigned int)__shfl((int)PKA[4 * c + 3], srcB_);     \
      u32x4 pw;                                                                \
      pw[0] = hi_ ? d0b : d0a;                                                 \
      pw[1] = hi_ ? d1b : d1a;                                                 \
      pw[2] = hi_ ? d2b : d2a;                                                 \
      pw[3] = hi_ ? d3b : d3a;                                                 \
      bf16x8 pf = __builtin_bit_cast(bf16x8, pw);                              \
      _Pragma("unroll") for (int dd = 0; dd < 4; ++dd)                         \
          OACC[dd] = __builtin_amdgcn_mfma_f32_16x16x32_bf16(                  \
              vf[2 * dd + c], pf, OACC[dd], 0, 0, 0);                          \
    }                                                                          \
  }
    PERMUTE_PV(pkA, oA)
    PERMUTE_PV(pkB, oB)
#undef PERMUTE_PV
  }

  // ---- two-phase LSE merge (reuse LDS) ----
#define MERGE_PHASE(MV, LV, OV, Q0)                                            \
  {                                                                            \
    if (lg == 0) { Msm[wid][l16] = MV; Lsm[wid][l16] = LV; }                   \
    _Pragma("unroll") for (int dd = 0; dd < 4; ++dd)                           \
      _Pragma("unroll") for (int r = 0; r < 4; ++r)                            \
          Osm[wid][dd][lg * 4 + r][l16] = OV[dd][r];                           \
    __syncthreads();                                                           \
    if (wid == 0) {                                                            \
      float M = Msm[0][l16];                                                   \
      _Pragma("unroll") for (int w = 1; w < 4; ++w) M = fmaxf(M, Msm[w][l16]); \
      float L = 0.0f;                                                          \
      f32x4 oc[4];                                                             \
      _Pragma("unroll") for (int dd = 0; dd < 4; ++dd) oc[dd] = (f32x4)0.0f;   \
      _Pragma("unroll") for (int w = 0; w < 4; ++w) {                          \
        float sc = exp2f(Msm[w][l16] - M);                                     \
        L += Lsm[w][l16] * sc;                                                 \
        _Pragma("unroll") for (int dd = 0; dd < 4; ++dd)                       \
          _Pragma("unroll") for (int r = 0; r < 4; ++r)                        \
              oc[dd][r] += Osm[w][dd][lg * 4 + r][l16] * sc;                   \
      }                                                                        \
      const float inv = 1.0f / L;                                              \
      float* op = out + ((size_t)b * SEQ + (Q0) + l16) * HEAD;                 \
      _Pragma("unroll") for (int dd = 0; dd < 4; ++dd)                         \
        _Pragma("unroll") for (int r = 0; r < 4; ++r)                          \
            op[16 * dd + lg * 4 + r] = oc[dd][r] * inv;                        \
    }                                                                          \
    __syncthreads();                                                           \
  }
  MERGE_PHASE(mA, lA, oA, q0a)
  MERGE_PHASE(mB, lB, oB, q0b)
#undef MERGE_PHASE
}

extern "C" void kernel_launch(void* const* d_in, const int* in_sizes, int n_in,
                              void* d_out, int out_size, void* d_ws, size_t ws_size,
                              hipStream_t stream) {
  (void)in_sizes; (void)n_in; (void)out_size; (void)ws_size;
  const float* x = (const float*)d_in[0];
  const float* W = (const float*)d_in[1];
  float* out = (float*)d_out;

  const size_t MB4 = (size_t)4 * 1024 * 1024;
  unsigned short* Wt = (unsigned short*)d_ws;                               // 384 KB
  unsigned short* PK = (unsigned short*)((char*)d_ws + 512 * 1024);         // 4 MB
  unsigned short* PQ = (unsigned short*)((char*)d_ws + 512 * 1024 + MB4);   // 4 MB
  unsigned short* PV = (unsigned short*)((char*)d_ws + 512 * 1024 + 2 * MB4); // 4 MB

  hipLaunchKernelGGL(wt_kernel, dim3((EMB * N3) / 256), dim3(256), 0, stream, W, Wt);
  hipLaunchKernelGGL(qkv_kernel, dim3((BATCH * SEQ) / BM), dim3(256), 0, stream, x, Wt, PK, PQ, PV);
  hipLaunchKernelGGL(attn_kernel, dim3(BATCH * 128), dim3(256), 0, stream, PK, PQ, PV, out);
}

// Round 11
// 101.822 us; speedup vs baseline: 1.6015x; 1.0424x over previous
//
#include <hip/hip_runtime.h>
#include <hip/hip_bf16.h>

#define BATCH 8
#define SEQ 4096
#define EMB 1024
#define HEAD 64
#define N3 192      // 3*HEAD: k | q | v

#define BM 64       // qkv block rows
#define BK 64       // qkv K-step
#define NT (EMB / BK)
#define LSTR 72     // padded LDS row stride in ushorts (64 + 8): 144B = 9*16B

typedef __attribute__((ext_vector_type(4))) float f32x4;
typedef __attribute__((ext_vector_type(8))) short bf16x8;
typedef __attribute__((ext_vector_type(4))) short short4v;
typedef __attribute__((ext_vector_type(4))) float float4v;
typedef __attribute__((ext_vector_type(2))) unsigned int u32x2;

#define LOG2E 1.4426950408889634f
#define QSCALE (0.125f * LOG2E)   // 1/sqrt(64) folded with log2e: scores in log2 domain

// Fragment-linear packing: each 1KB sub-tile holds a 16-row x 32-col bf16
// block, ordered so lane (l16,lg) reads its 16B MFMA fragment at
// subtile_base + (l16*4+lg)*16B  ->  one contiguous 1KB burst per wave-load.
// PK/PQ: [b][i=row/16][kh=d/32][512]   PV: [b][s=kv/64][dd=d/16][c=kv32][512]

static __device__ __forceinline__ unsigned short f2bf(float f) {
  unsigned int x = __builtin_bit_cast(unsigned int, f);
  x += 0x7fffu + ((x >> 16) & 1u);   // RTNE
  return (unsigned short)(x >> 16);
}

// --- Kernel 1: W [1024][192] f32 -> Wt [192][1024] bf16 ---
__global__ __launch_bounds__(256) void wt_kernel(const float* __restrict__ W,
                                                 unsigned short* __restrict__ Wt) {
  int idx = blockIdx.x * 256 + threadIdx.x;
  int k = idx / N3, c = idx % N3;
  Wt[(size_t)c * EMB + k] = f2bf(W[idx]);
}

// --- Kernel 2: canonical LDS-staged GEMM, epilogue packs fragment-linear ---
__global__ __launch_bounds__(256, 2) void qkv_kernel(const float* __restrict__ x,
                                                     const unsigned short* __restrict__ Wt,
                                                     unsigned short* __restrict__ PK,
                                                     unsigned short* __restrict__ PQ,
                                                     unsigned short* __restrict__ PV) {
  __shared__ unsigned short Asm[2][BM][LSTR];    // 2 x 64 x 144B = 18.4 KB
  __shared__ unsigned short Bsm[2][N3][LSTR];    // 2 x 192 x 144B = 55.3 KB

  const int tid = threadIdx.x;
  const int wid = tid >> 6;
  const int lane = tid & 63;
  const int l16 = lane & 15;
  const int lg = lane >> 4;
  const int m0 = blockIdx.x * BM;

  const int ar0 = tid >> 4;        // A row base: +16*i, i<4
  const int ac4 = tid & 15;        // A float4-chunk in row
  const int br0 = tid >> 3;        // B row base: +32*i, i<6
  const int bc = tid & 7;          // B bf16x8-chunk in row

  const float* xa = x + (size_t)(m0 + ar0) * EMB + ac4 * 4;
  const unsigned short* wb = Wt + (size_t)br0 * EMB + bc * 8;

  f32x4 acc[4][3];
#pragma unroll
  for (int mi = 0; mi < 4; ++mi)
#pragma unroll
    for (int ni = 0; ni < 3; ++ni) acc[mi][ni] = (f32x4)0.0f;

  float4v av[4];
  bf16x8 bv[6];

#define ISSUE_LOADS(K0)                                                        \
  {                                                                            \
    _Pragma("unroll") for (int i = 0; i < 4; ++i)                              \
        av[i] = *(const float4v*)(xa + (size_t)(16 * i) * EMB + (K0));         \
    _Pragma("unroll") for (int i = 0; i < 6; ++i)                              \
        bv[i] = *(const bf16x8*)(wb + (size_t)(32 * i) * EMB + (K0));          \
  }

#define WRITE_LDS(BUF)                                                         \
  {                                                                            \
    _Pragma("unroll") for (int i = 0; i < 4; ++i) {                            \
      short4v p;                                                               \
      _Pragma("unroll") for (int j = 0; j < 4; ++j)                            \
          p[j] = (short)f2bf(av[i][j]);                                        \
      *(short4v*)&Asm[BUF][ar0 + 16 * i][ac4 * 4] = p;                         \
    }                                                                          \
    _Pragma("unroll") for (int i = 0; i < 6; ++i)                              \
        *(bf16x8*)&Bsm[BUF][br0 + 32 * i][bc * 8] = bv[i];                     \
  }

#define COMPUTE(BUF)                                                           \
  {                                                                            \
    _Pragma("unroll") for (int kh = 0; kh < 2; ++kh) {                         \
      bf16x8 af[4], bfr[3];                                                    \
      _Pragma("unroll") for (int mi = 0; mi < 4; ++mi)                         \
          af[mi] = *(const bf16x8*)&Asm[BUF][mi * 16 + l16][kh * 32 + lg * 8]; \
      _Pragma("unroll") for (int ni = 0; ni < 3; ++ni)                         \
          bfr[ni] = *(const bf16x8*)&Bsm[BUF][wid * 48 + ni * 16 + l16][kh * 32 + lg * 8]; \
      _Pragma("unroll") for (int mi = 0; mi < 4; ++mi)                         \
        _Pragma("unroll") for (int ni = 0; ni < 3; ++ni)                       \
            acc[mi][ni] = __builtin_amdgcn_mfma_f32_16x16x32_bf16(             \
                af[mi], bfr[ni], acc[mi][ni], 0, 0, 0);                        \
    }                                                                          \
  }

  ISSUE_LOADS(0)
  WRITE_LDS(0)
  __syncthreads();

  int cur = 0;
  for (int t = 0; t < NT; ++t) {
    if (t < NT - 1) ISSUE_LOADS((t + 1) * BK)
    COMPUTE(cur)
    if (t < NT - 1) {
      WRITE_LDS(cur ^ 1)
    }
    __syncthreads();
    cur ^= 1;
  }
#undef ISSUE_LOADS
#undef WRITE_LDS
#undef COMPUTE

  // epilogue: D col = n (l16-resident), row = m0 + mi*16 + lg*4 + r
#pragma unroll
  for (int mi = 0; mi < 4; ++mi) {
#pragma unroll
    for (int ni = 0; ni < 3; ++ni) {
      const int n = wid * 48 + ni * 16 + l16;
#pragma unroll
      for (int r = 0; r < 4; ++r) {
        const int row = m0 + mi * 16 + lg * 4 + r;
        const int bb = row >> 12;
        const int ss = row & (SEQ - 1);
        const float v = acc[mi][ni][r];
        if (n < 64) {            // K
          PK[(((size_t)bb * 256 + (ss >> 4)) * 2 + (n >> 5)) * 512 +
             (ss & 15) * 32 + (n & 31)] = f2bf(v);
        } else if (n < 128) {    // Q (pre-scaled 1/sqrt(64) * log2e)
          const int d = n - 64;
          PQ[(((size_t)bb * 256 + (ss >> 4)) * 2 + (d >> 5)) * 512 +
             (ss & 15) * 32 + (d & 31)] = f2bf(v * QSCALE);
        } else {                 // V
          const int d = n - 128;
          PV[(((size_t)bb * 64 + (ss >> 6)) * 8 + (d >> 4) * 2 + ((ss >> 5) & 1)) * 512 +
             (d & 15) * 32 + (ss & 31)] = f2bf(v);
        }
      }
    }
  }
}

// --- Kernel 3: causal flash attention. 1024 blocks, 4 waves. Wave owns two
// consecutive 16-row q-chunks (shared K loads) over its KV-split range.
// Chunk A processed fully then chunk B (register economy, no spill).
// P permute via per-wave LDS transpose (4x ds_write_b64 + 2x ds_read_b128).
// Block->p map balances per-CU work (same-CU blocks: i,127-i,32+i,95-i).
__global__ __launch_bounds__(256, 4) void attn_kernel(const unsigned short* __restrict__ PK,
                                                      const unsigned short* __restrict__ PQ,
                                                      const unsigned short* __restrict__ PV,
                                                      float* __restrict__ out) {
  __shared__ float Msm[4][16];
  __shared__ float Lsm[4][16];
  __shared__ float Osm[4][4][16][17];          // [wave][dd][d-row][q] (+1 pad)
  __shared__ unsigned short Pl[4][2][16][LSTR];  // per-wave P^T double buffer [q][kv]

  const int tid = threadIdx.x;
  const int wid = tid >> 6;
  const int lane = tid & 63;
  const int l16 = lane & 15;
  const int lg = lane >> 4;
  const int lam = (l16 * 4 + lg) * 8;   // lane's ushort offset in a 1KB sub-tile

  const int Bid = blockIdx.x;
  const int b = Bid & 7;                     // batch (XCD affinity)
  const int i_ = (Bid >> 3) & 31;
  const int j_ = Bid >> 8;
  const int p = (j_ == 0) ? i_ : (j_ == 1) ? (127 - i_) : (j_ == 2) ? (32 + i_) : (95 - i_);
  const int qc0 = 2 * p, qc1 = 2 * p + 1;
  const int q0a = qc0 * 16, q0b = qc1 * 16;
  const int T_total = (q0b + 16 + 63) >> 6;  // tiles covering KV [0, q0b+16)
  const int t0 = (wid * T_total) >> 2;
  const int t1 = ((wid + 1) * T_total) >> 2;

  const unsigned short* pkb = PK + (size_t)b * 256 * 1024;
  const unsigned short* pqb = PQ + (size_t)b * 256 * 1024;
  const unsigned short* pvb = PV + (size_t)b * 64 * 8 * 512;

  // Q fragments for both chunks (B-operand of S^T mfma)
  bf16x8 qa0 = *(const bf16x8*)(pqb + ((size_t)qc0 * 2 + 0) * 512 + lam);
  bf16x8 qa1 = *(const bf16x8*)(pqb + ((size_t)qc0 * 2 + 1) * 512 + lam);
  bf16x8 qb0 = *(const bf16x8*)(pqb + ((size_t)qc1 * 2 + 0) * 512 + lam);
  bf16x8 qb1 = *(const bf16x8*)(pqb + ((size_t)qc1 * 2 + 1) * 512 + lam);

  f32x4 oA[4], oB[4];
#pragma unroll
  for (int dd = 0; dd < 4; ++dd) { oA[dd] = (f32x4)0.0f; oB[dd] = (f32x4)0.0f; }
  float mA = -3.0e38f, lA = 0.0f, mB = -3.0e38f, lB = 0.0f;

  for (int it = t0; it < t1; ++it) {
    const int kv0 = it << 6;

    // QK^T for both chunks; kf transient per t (4 regs live at a time)
    f32x4 s0[4], s1[4];
#pragma unroll
    for (int t = 0; t < 4; ++t) {
      const unsigned short* kp = pkb + ((size_t)(it * 4 + t) * 2) * 512 + lam;
      bf16x8 kfa = *(const bf16x8*)(kp);
      bf16x8 kfb = *(const bf16x8*)(kp + 512);
      f32x4 z = (f32x4)0.0f;
      z = __builtin_amdgcn_mfma_f32_16x16x32_bf16(kfa, qa0, z, 0, 0, 0);
      s0[t] = __builtin_amdgcn_mfma_f32_16x16x32_bf16(kfb, qa1, z, 0, 0, 0);
      z = (f32x4)0.0f;
      z = __builtin_amdgcn_mfma_f32_16x16x32_bf16(kfa, qb0, z, 0, 0, 0);
      s1[t] = __builtin_amdgcn_mfma_f32_16x16x32_bf16(kfb, qb1, z, 0, 0, 0);
    }

    // V fragments issued early (consumed at PV A / PV B)
    bf16x8 vf[8];
#pragma unroll
    for (int dd = 0; dd < 4; ++dd) {
      const unsigned short* vp = pvb + ((size_t)it * 8 + dd * 2) * 512 + lam;
      vf[2 * dd] = *(const bf16x8*)(vp);
      vf[2 * dd + 1] = *(const bf16x8*)(vp + 512);
    }

    // ---- chunk A: mask, softmax (log2 domain), P->LDS, PV ----
    if (kv0 + 64 > q0a) {
      const int base = kv0 + lg * 4 - q0a - l16;
#pragma unroll
      for (int t = 0; t < 4; ++t)
#pragma unroll
        for (int r = 0; r < 4; ++r)
          if (base + 16 * t + r > 0) s0[t][r] = -3.0e38f;
    }
    {
      float mx = s0[0][0];
#pragma unroll
      for (int t = 0; t < 4; ++t)
#pragma unroll
        for (int r = 0; r < 4; ++r) mx = fmaxf(mx, s0[t][r]);
      mx = fmaxf(mx, __shfl_xor(mx, 16));
      mx = fmaxf(mx, __shfl_xor(mx, 32));
      if (!__all(mx <= mA)) {
        float mn = fmaxf(mA, mx);
        float al = exp2f(mA - mn);
        mA = mn; lA *= al;
#pragma unroll
        for (int dd = 0; dd < 4; ++dd) oA[dd] *= al;
      }
      float ps = 0.0f;
#pragma unroll
      for (int t = 0; t < 4; ++t) {
        float p0 = exp2f(s0[t][0] - mA);
        float p1 = exp2f(s0[t][1] - mA);
        float p2 = exp2f(s0[t][2] - mA);
        float p3 = exp2f(s0[t][3] - mA);
        ps += (p0 + p1) + (p2 + p3);
        u32x2 w;
        w[0] = (__builtin_bit_cast(unsigned int, p1) & 0xFFFF0000u) |
               (__builtin_bit_cast(unsigned int, p0) >> 16);
        w[1] = (__builtin_bit_cast(unsigned int, p3) & 0xFFFF0000u) |
               (__builtin_bit_cast(unsigned int, p2) >> 16);
        *(u32x2*)&Pl[wid][0][l16][16 * t + lg * 4] = w;   // P^T[q=l16][kv=16t+4lg..+3]
      }
      ps += __shfl_xor(ps, 16);
      ps += __shfl_xor(ps, 32);
      lA += ps;
    }
    {
      bf16x8 pf0 = *(const bf16x8*)&Pl[wid][0][l16][lg * 8];        // kv 0..31 frag
      bf16x8 pf1 = *(const bf16x8*)&Pl[wid][0][l16][32 + lg * 8];   // kv 32..63 frag
#pragma unroll
      for (int dd = 0; dd < 4; ++dd) {
        oA[dd] = __builtin_amdgcn_mfma_f32_16x16x32_bf16(vf[2 * dd], pf0, oA[dd], 0, 0, 0);
        oA[dd] = __builtin_amdgcn_mfma_f32_16x16x32_bf16(vf[2 * dd + 1], pf1, oA[dd], 0, 0, 0);
      }
    }

    // ---- chunk B ----
    if (kv0 + 64 > q0b) {
      const int base = kv0 + lg * 4 - q0b - l16;
#pragma unroll
      for (int t = 0; t < 4; ++t)
#pragma unroll
        for (int r = 0; r < 4; ++r)
          if (base + 16 * t + r > 0) s1[t][r] = -3.0e38f;
    }
    {
      float mx = s1[0][0];
#pragma unroll
      for (int t = 0; t < 4; ++t)
#pragma unroll
        for (int r = 0; r < 4; ++r) mx = fmaxf(mx, s1[t][r]);
      mx = fmaxf(mx, __shfl_xor(mx, 16));
      mx = fmaxf(mx, __shfl_xor(mx, 32));
      if (!__all(mx <= mB)) {
        float mn = fmaxf(mB, mx);
        float al = exp2f(mB - mn);
        mB = mn; lB *= al;
#pragma unroll
        for (int dd = 0; dd < 4; ++dd) oB[dd] *= al;
      }
      float ps = 0.0f;
#pragma unroll
      for (int t = 0; t < 4; ++t) {
        float p0 = exp2f(s1[t][0] - mB);
        float p1 = exp2f(s1[t][1] - mB);
        float p2 = exp2f(s1[t][2] - mB);
        float p3 = exp2f(s1[t][3] - mB);
        ps += (p0 + p1) + (p2 + p3);
        u32x2 w;
        w[0] = (__builtin_bit_cast(unsigned int, p1) & 0xFFFF0000u) |
               (__builtin_bit_cast(unsigned int, p0) >> 16);
        w[1] = (__builtin_bit_cast(unsigned int, p3) & 0xFFFF0000u) |
               (__builtin_bit_cast(unsigned int, p2) >> 16);
        *(u32x2*)&Pl[wid][1][l16][16 * t + lg * 4] = w;
      }
      ps += __shfl_xor(ps, 16);
      ps += __shfl_xor(ps, 32);
      lB += ps;
    }
    {
      bf16x8 pf0 = *(const bf16x8*)&Pl[wid][1][l16][lg * 8];
      bf16x8 pf1 = *(const bf16x8*)&Pl[wid][1][l16][32 + lg * 8];
#pragma unroll
      for (int dd = 0; dd < 4; ++dd) {
        oB[dd] = __builtin_amdgcn_mfma_f32_16x16x32_bf16(vf[2 * dd], pf0, oB[dd], 0, 0, 0);
        oB[dd] = __builtin_amdgcn_mfma_f32_16x16x32_bf16(vf[2 * dd + 1], pf1, oB[dd], 0, 0, 0);
      }
    }
  }

  // ---- two-phase LSE merge (reuse LDS) ----
#define MERGE_PHASE(MV, LV, OV, Q0)                                            \
  {                                                                            \
    if (lg == 0) { Msm[wid][l16] = MV; Lsm[wid][l16] = LV; }                   \
    _Pragma("unroll") for (int dd = 0; dd < 4; ++dd)                           \
      _Pragma("unroll") for (int r = 0; r < 4; ++r)                            \
          Osm[wid][dd][lg * 4 + r][l16] = OV[dd][r];                           \
    __syncthreads();                                                           \
    if (wid == 0) {                                                            \
      float M = Msm[0][l16];                                                   \
      _Pragma("unroll") for (int w = 1; w < 4; ++w) M = fmaxf(M, Msm[w][l16]); \
      float L = 0.0f;                                                          \
      f32x4 oc[4];                                                             \
      _Pragma("unroll") for (int dd = 0; dd < 4; ++dd) oc[dd] = (f32x4)0.0f;   \
      _Pragma("unroll") for (int w = 0; w < 4; ++w) {                          \
        float sc = exp2f(Msm[w][l16] - M);                                     \
        L += Lsm[w][l16] * sc;                                                 \
        _Pragma("unroll") for (int dd = 0; dd < 4; ++dd)                       \
          _Pragma("unroll") for (int r = 0; r < 4; ++r)                        \
              oc[dd][r] += Osm[w][dd][lg * 4 + r][l16] * sc;                   \
      }                                                                        \
      const float inv = 1.0f / L;                                              \
      float* op = out + ((size_t)b * SEQ + (Q0) + l16) * HEAD;                 \
      _Pragma("unroll") for (int dd = 0; dd < 4; ++dd)                         \
        _Pragma("unroll") for (int r = 0; r < 4; ++r)                          \
            op[16 * dd + lg * 4 + r] = oc[dd][r] * inv;                        \
    }                                                                          \
    __syncthreads();                                                           \
  }
  MERGE_PHASE(mA, lA, oA, q0a)
  MERGE_PHASE(mB, lB, oB, q0b)
#undef MERGE_PHASE
}

extern "C" void kernel_launch(void* const* d_in, const int* in_sizes, int n_in,
                              void* d_out, int out_size, void* d_ws, size_t ws_size,
                              hipStream_t stream) {
  (void)in_sizes; (void)n_in; (void)out_size; (void)ws_size;
  const float* x = (const float*)d_in[0];
  const float* W = (const float*)d_in[1];
  float* out = (float*)d_out;

  const size_t MB4 = (size_t)4 * 1024 * 1024;
  unsigned short* Wt = (unsigned short*)d_ws;                               // 384 KB
  unsigned short* PK = (unsigned short*)((char*)d_ws + 512 * 1024);         // 4 MB
  unsigned short* PQ = (unsigned short*)((char*)d_ws + 512 * 1024 + MB4);   // 4 MB
  unsigned short* PV = (unsigned short*)((char*)d_ws + 512 * 1024 + 2 * MB4); // 4 MB

  hipLaunchKernelGGL(wt_kernel, dim3((EMB * N3) / 256), dim3(256), 0, stream, W, Wt);
  hipLaunchKernelGGL(qkv_kernel, dim3((BATCH * SEQ) / BM), dim3(256), 0, stream, x, Wt, PK, PQ, PV);
  hipLaunchKernelGGL(attn_kernel, dim3(BATCH * 128), dim3(256), 0, stream, PK, PQ, PV, out);
}

// Round 12
// 86.356 us; speedup vs baseline: 1.8883x; 1.1791x over previous
//
#include <hip/hip_runtime.h>
#include <hip/hip_bf16.h>

#define BATCH 8
#define SEQ 4096
#define EMB 1024
#define HEAD 64
#define N3 192      // 3*HEAD: k | q | v

#define BM 64       // qkv block rows
#define BK 64       // qkv K-step
#define NT (EMB / BK)
#define LSTR 72     // padded LDS row stride in ushorts (64 + 8): 144B = 9*16B

typedef __attribute__((ext_vector_type(4))) float f32x4;
typedef __attribute__((ext_vector_type(8))) short bf16x8;
typedef __attribute__((ext_vector_type(4))) short short4v;
typedef __attribute__((ext_vector_type(4))) float float4v;
typedef __attribute__((ext_vector_type(2))) unsigned int u32x2;

#define LOG2E 1.4426950408889634f
#define QSCALE (0.125f * LOG2E)   // 1/sqrt(64) folded with log2e: scores in log2 domain

// Fragment-linear packing: each 1KB sub-tile holds a 16-row x 32-col bf16
// block, ordered so lane (l16,lg) reads its 16B MFMA fragment at
// subtile_base + (l16*4+lg)*16B  ->  one contiguous 1KB burst per wave-load.
// PK/PQ: [b][i=row/16][kh=d/32][512]   PV: [b][s=kv/64][dd=d/16][c=kv32][512]

static __device__ __forceinline__ unsigned short f2bf(float f) {
  unsigned int x = __builtin_bit_cast(unsigned int, f);
  x += 0x7fffu + ((x >> 16) & 1u);   // RTNE
  return (unsigned short)(x >> 16);
}

// --- Kernel 1: W [1024][192] f32 -> Wt [192][1024] bf16 ---
__global__ __launch_bounds__(256) void wt_kernel(const float* __restrict__ W,
                                                 unsigned short* __restrict__ Wt) {
  int idx = blockIdx.x * 256 + threadIdx.x;
  int k = idx / N3, c = idx % N3;
  Wt[(size_t)c * EMB + k] = f2bf(W[idx]);
}

// --- Kernel 2: canonical LDS-staged GEMM, epilogue packs fragment-linear ---
__global__ __launch_bounds__(256, 2) void qkv_kernel(const float* __restrict__ x,
                                                     const unsigned short* __restrict__ Wt,
                                                     unsigned short* __restrict__ PK,
                                                     unsigned short* __restrict__ PQ,
                                                     unsigned short* __restrict__ PV) {
  __shared__ unsigned short Asm[2][BM][LSTR];    // 2 x 64 x 144B = 18.4 KB
  __shared__ unsigned short Bsm[2][N3][LSTR];    // 2 x 192 x 144B = 55.3 KB

  const int tid = threadIdx.x;
  const int wid = tid >> 6;
  const int lane = tid & 63;
  const int l16 = lane & 15;
  const int lg = lane >> 4;
  const int m0 = blockIdx.x * BM;

  const int ar0 = tid >> 4;        // A row base: +16*i, i<4
  const int ac4 = tid & 15;        // A float4-chunk in row
  const int br0 = tid >> 3;        // B row base: +32*i, i<6
  const int bc = tid & 7;          // B bf16x8-chunk in row

  const float* xa = x + (size_t)(m0 + ar0) * EMB + ac4 * 4;
  const unsigned short* wb = Wt + (size_t)br0 * EMB + bc * 8;

  f32x4 acc[4][3];
#pragma unroll
  for (int mi = 0; mi < 4; ++mi)
#pragma unroll
    for (int ni = 0; ni < 3; ++ni) acc[mi][ni] = (f32x4)0.0f;

  float4v av[4];
  bf16x8 bv[6];

#define ISSUE_LOADS(K0)                                                        \
  {                                                                            \
    _Pragma("unroll") for (int i = 0; i < 4; ++i)                              \
        av[i] = *(const float4v*)(xa + (size_t)(16 * i) * EMB + (K0));         \
    _Pragma("unroll") for (int i = 0; i < 6; ++i)                              \
        bv[i] = *(const bf16x8*)(wb + (size_t)(32 * i) * EMB + (K0));          \
  }

#define WRITE_LDS(BUF)                                                         \
  {                                                                            \
    _Pragma("unroll") for (int i = 0; i < 4; ++i) {                            \
      short4v p;                                                               \
      _Pragma("unroll") for (int j = 0; j < 4; ++j)                            \
          p[j] = (short)f2bf(av[i][j]);                                        \
      *(short4v*)&Asm[BUF][ar0 + 16 * i][ac4 * 4] = p;                         \
    }                                                                          \
    _Pragma("unroll") for (int i = 0; i < 6; ++i)                              \
        *(bf16x8*)&Bsm[BUF][br0 + 32 * i][bc * 8] = bv[i];                     \
  }

#define COMPUTE(BUF)                                                           \
  {                                                                            \
    _Pragma("unroll") for (int kh = 0; kh < 2; ++kh) {                         \
      bf16x8 af[4], bfr[3];                                                    \
      _Pragma("unroll") for (int mi = 0; mi < 4; ++mi)                         \
          af[mi] = *(const bf16x8*)&Asm[BUF][mi * 16 + l16][kh * 32 + lg * 8]; \
      _Pragma("unroll") for (int ni = 0; ni < 3; ++ni)                         \
          bfr[ni] = *(const bf16x8*)&Bsm[BUF][wid * 48 + ni * 16 + l16][kh * 32 + lg * 8]; \
      _Pragma("unroll") for (int mi = 0; mi < 4; ++mi)                         \
        _Pragma("unroll") for (int ni = 0; ni < 3; ++ni)                       \
            acc[mi][ni] = __builtin_amdgcn_mfma_f32_16x16x32_bf16(             \
                af[mi], bfr[ni], acc[mi][ni], 0, 0, 0);                        \
    }                                                                          \
  }

  ISSUE_LOADS(0)
  WRITE_LDS(0)
  __syncthreads();

  int cur = 0;
  for (int t = 0; t < NT; ++t) {
    if (t < NT - 1) ISSUE_LOADS((t + 1) * BK)
    COMPUTE(cur)
    if (t < NT - 1) {
      WRITE_LDS(cur ^ 1)
    }
    __syncthreads();
    cur ^= 1;
  }
#undef ISSUE_LOADS
#undef WRITE_LDS
#undef COMPUTE

  // epilogue: D col = n (l16-resident), row = m0 + mi*16 + lg*4 + r
#pragma unroll
  for (int mi = 0; mi < 4; ++mi) {
#pragma unroll
    for (int ni = 0; ni < 3; ++ni) {
      const int n = wid * 48 + ni * 16 + l16;
#pragma unroll
      for (int r = 0; r < 4; ++r) {
        const int row = m0 + mi * 16 + lg * 4 + r;
        const int bb = row >> 12;
        const int ss = row & (SEQ - 1);
        const float v = acc[mi][ni][r];
        if (n < 64) {            // K
          PK[(((size_t)bb * 256 + (ss >> 4)) * 2 + (n >> 5)) * 512 +
             (ss & 15) * 32 + (n & 31)] = f2bf(v);
        } else if (n < 128) {    // Q (pre-scaled 1/sqrt(64) * log2e)
          const int d = n - 64;
          PQ[(((size_t)bb * 256 + (ss >> 4)) * 2 + (d >> 5)) * 512 +
             (ss & 15) * 32 + (d & 31)] = f2bf(v * QSCALE);
        } else {                 // V
          const int d = n - 128;
          PV[(((size_t)bb * 64 + (ss >> 6)) * 8 + (d >> 4) * 2 + ((ss >> 5) & 1)) * 512 +
             (d & 15) * 32 + (ss & 31)] = f2bf(v);
        }
      }
    }
  }
}

// --- Kernel 3: causal flash attention. 1024 blocks, 4 waves. Wave owns two
// consecutive 16-row q-chunks over its KV-split range. Running pointers
// (strength-reduced addressing), cross-iteration K prefetch, setprio around
// MFMA clusters, per-wave LDS P-transpose, log2-domain softmax.
__global__ __launch_bounds__(256, 3) void attn_kernel(const unsigned short* __restrict__ PK,
                                                      const unsigned short* __restrict__ PQ,
                                                      const unsigned short* __restrict__ PV,
                                                      float* __restrict__ out) {
  __shared__ float Msm[4][16];
  __shared__ float Lsm[4][16];
  __shared__ float Osm[4][4][16][17];            // [wave][dd][d-row][q] (+1 pad)
  __shared__ unsigned short Pl[4][2][16][LSTR];  // per-wave P^T double buffer [q][kv]

  const int tid = threadIdx.x;
  const int wid = tid >> 6;
  const int lane = tid & 63;
  const int l16 = lane & 15;
  const int lg = lane >> 4;
  const int lam = (l16 * 4 + lg) * 8;   // lane's ushort offset in a 1KB sub-tile

  const int Bid = blockIdx.x;
  const int b = Bid & 7;                     // batch (XCD affinity)
  const int i_ = (Bid >> 3) & 31;
  const int j_ = Bid >> 8;
  const int p = (j_ == 0) ? i_ : (j_ == 1) ? (127 - i_) : (j_ == 2) ? (32 + i_) : (95 - i_);
  const int qc0 = 2 * p, qc1 = 2 * p + 1;
  const int q0a = qc0 * 16, q0b = qc1 * 16;
  const int T_total = (q0b + 16 + 63) >> 6;  // tiles covering KV [0, q0b+16)
  const int t0 = (wid * T_total) >> 2;
  const int t1 = ((wid + 1) * T_total) >> 2;

  const unsigned short* pqb = PQ + (size_t)b * 256 * 1024;

  // Q fragments for both chunks (B-operand of S^T mfma)
  bf16x8 qa0 = *(const bf16x8*)(pqb + ((size_t)qc0 * 2 + 0) * 512 + lam);
  bf16x8 qa1 = *(const bf16x8*)(pqb + ((size_t)qc0 * 2 + 1) * 512 + lam);
  bf16x8 qb0 = *(const bf16x8*)(pqb + ((size_t)qc1 * 2 + 0) * 512 + lam);
  bf16x8 qb1 = *(const bf16x8*)(pqb + ((size_t)qc1 * 2 + 1) * 512 + lam);

  f32x4 oA[4], oB[4];
#pragma unroll
  for (int dd = 0; dd < 4; ++dd) { oA[dd] = (f32x4)0.0f; oB[dd] = (f32x4)0.0f; }
  float mA = -3.0e38f, lA = 0.0f, mB = -3.0e38f, lB = 0.0f;

  // running pointers (strength-reduced): K tile = 4096 ushorts, V tile = 4096
  const unsigned short* kp = PK + (size_t)b * 256 * 1024 + (size_t)t0 * 4096 + lam;
  const unsigned short* vp = PV + (size_t)b * 64 * 8 * 512 + (size_t)t0 * 4096 + lam;

  if (t0 < t1) {
    // preload K tile t0
    bf16x8 kf[8], kn[8];
#pragma unroll
    for (int t = 0; t < 4; ++t) {
      kf[2 * t] = *(const bf16x8*)(kp + t * 1024);
      kf[2 * t + 1] = *(const bf16x8*)(kp + t * 1024 + 512);
    }

    for (int it = t0; it < t1; ++it) {
      const int kv0 = it << 6;

      // prefetch next K tile (unconditional; last read lands in adjacent ws
      // region, never consumed)
#pragma unroll
      for (int t = 0; t < 4; ++t) {
        kn[2 * t] = *(const bf16x8*)(kp + 4096 + t * 1024);
        kn[2 * t + 1] = *(const bf16x8*)(kp + 4096 + t * 1024 + 512);
      }
      // V fragments for this tile (consumed at PV A / PV B)
      bf16x8 vf[8];
#pragma unroll
      for (int dd = 0; dd < 4; ++dd) {
        vf[2 * dd] = *(const bf16x8*)(vp + dd * 1024);
        vf[2 * dd + 1] = *(const bf16x8*)(vp + dd * 1024 + 512);
      }

      // QK^T for both chunks from kf
      f32x4 s0[4], s1[4];
      __builtin_amdgcn_s_setprio(1);
#pragma unroll
      for (int t = 0; t < 4; ++t) {
        f32x4 z = (f32x4)0.0f;
        z = __builtin_amdgcn_mfma_f32_16x16x32_bf16(kf[2 * t], qa0, z, 0, 0, 0);
        s0[t] = __builtin_amdgcn_mfma_f32_16x16x32_bf16(kf[2 * t + 1], qa1, z, 0, 0, 0);
        z = (f32x4)0.0f;
        z = __builtin_amdgcn_mfma_f32_16x16x32_bf16(kf[2 * t], qb0, z, 0, 0, 0);
        s1[t] = __builtin_amdgcn_mfma_f32_16x16x32_bf16(kf[2 * t + 1], qb1, z, 0, 0, 0);
      }
      __builtin_amdgcn_s_setprio(0);

      // ---- chunk A: mask, softmax (log2 domain), P->LDS, PV ----
      if (kv0 + 64 > q0a) {
        const int base = kv0 + lg * 4 - q0a - l16;
#pragma unroll
        for (int t = 0; t < 4; ++t)
#pragma unroll
          for (int r = 0; r < 4; ++r)
            if (base + 16 * t + r > 0) s0[t][r] = -3.0e38f;
      }
      {
        float mx = s0[0][0];
#pragma unroll
        for (int t = 0; t < 4; ++t)
#pragma unroll
          for (int r = 0; r < 4; ++r) mx = fmaxf(mx, s0[t][r]);
        mx = fmaxf(mx, __shfl_xor(mx, 16));
        mx = fmaxf(mx, __shfl_xor(mx, 32));
        if (!__all(mx <= mA)) {
          float mn = fmaxf(mA, mx);
          float al = exp2f(mA - mn);
          mA = mn; lA *= al;
#pragma unroll
          for (int dd = 0; dd < 4; ++dd) oA[dd] *= al;
        }
        float ps = 0.0f;
#pragma unroll
        for (int t = 0; t < 4; ++t) {
          float p0 = exp2f(s0[t][0] - mA);
          float p1 = exp2f(s0[t][1] - mA);
          float p2 = exp2f(s0[t][2] - mA);
          float p3 = exp2f(s0[t][3] - mA);
          ps += (p0 + p1) + (p2 + p3);
          u32x2 w;
          w[0] = (__builtin_bit_cast(unsigned int, p1) & 0xFFFF0000u) |
                 (__builtin_bit_cast(unsigned int, p0) >> 16);
          w[1] = (__builtin_bit_cast(unsigned int, p3) & 0xFFFF0000u) |
                 (__builtin_bit_cast(unsigned int, p2) >> 16);
          *(u32x2*)&Pl[wid][0][l16][16 * t + lg * 4] = w;   // P^T[q=l16][kv]
        }
        ps += __shfl_xor(ps, 16);
        ps += __shfl_xor(ps, 32);
        lA += ps;
      }
      {
        bf16x8 pf0 = *(const bf16x8*)&Pl[wid][0][l16][lg * 8];
        bf16x8 pf1 = *(const bf16x8*)&Pl[wid][0][l16][32 + lg * 8];
        __builtin_amdgcn_s_setprio(1);
#pragma unroll
        for (int dd = 0; dd < 4; ++dd) {
          oA[dd] = __builtin_amdgcn_mfma_f32_16x16x32_bf16(vf[2 * dd], pf0, oA[dd], 0, 0, 0);
          oA[dd] = __builtin_amdgcn_mfma_f32_16x16x32_bf16(vf[2 * dd + 1], pf1, oA[dd], 0, 0, 0);
        }
        __builtin_amdgcn_s_setprio(0);
      }

      // ---- chunk B ----
      if (kv0 + 64 > q0b) {
        const int base = kv0 + lg * 4 - q0b - l16;
#pragma unroll
        for (int t = 0; t < 4; ++t)
#pragma unroll
          for (int r = 0; r < 4; ++r)
            if (base + 16 * t + r > 0) s1[t][r] = -3.0e38f;
      }
      {
        float mx = s1[0][0];
#pragma unroll
        for (int t = 0; t < 4; ++t)
#pragma unroll
          for (int r = 0; r < 4; ++r) mx = fmaxf(mx, s1[t][r]);
        mx = fmaxf(mx, __shfl_xor(mx, 16));
        mx = fmaxf(mx, __shfl_xor(mx, 32));
        if (!__all(mx <= mB)) {
          float mn = fmaxf(mB, mx);
          float al = exp2f(mB - mn);
          mB = mn; lB *= al;
#pragma unroll
          for (int dd = 0; dd < 4; ++dd) oB[dd] *= al;
        }
        float ps = 0.0f;
#pragma unroll
        for (int t = 0; t < 4; ++t) {
          float p0 = exp2f(s1[t][0] - mB);
          float p1 = exp2f(s1[t][1] - mB);
          float p2 = exp2f(s1[t][2] - mB);
          float p3 = exp2f(s1[t][3] - mB);
          ps += (p0 + p1) + (p2 + p3);
          u32x2 w;
          w[0] = (__builtin_bit_cast(unsigned int, p1) & 0xFFFF0000u) |
                 (__builtin_bit_cast(unsigned int, p0) >> 16);
          w[1] = (__builtin_bit_cast(unsigned int, p3) & 0xFFFF0000u) |
                 (__builtin_bit_cast(unsigned int, p2) >> 16);
          *(u32x2*)&Pl[wid][1][l16][16 * t + lg * 4] = w;
        }
        ps += __shfl_xor(ps, 16);
        ps += __shfl_xor(ps, 32);
        lB += ps;
      }
      {
        bf16x8 pf0 = *(const bf16x8*)&Pl[wid][1][l16][lg * 8];
        bf16x8 pf1 = *(const bf16x8*)&Pl[wid][1][l16][32 + lg * 8];
        __builtin_amdgcn_s_setprio(1);
#pragma unroll
        for (int dd = 0; dd < 4; ++dd) {
          oB[dd] = __builtin_amdgcn_mfma_f32_16x16x32_bf16(vf[2 * dd], pf0, oB[dd], 0, 0, 0);
          oB[dd] = __builtin_amdgcn_mfma_f32_16x16x32_bf16(vf[2 * dd + 1], pf1, oB[dd], 0, 0, 0);
        }
        __builtin_amdgcn_s_setprio(0);
      }

#pragma unroll
      for (int j = 0; j < 8; ++j) kf[j] = kn[j];
      kp += 4096;
      vp += 4096;
    }
  }

  // ---- two-phase LSE merge (reuse LDS) ----
#define MERGE_PHASE(MV, LV, OV, Q0)                                            \
  {                                                                            \
    if (lg == 0) { Msm[wid][l16] = MV; Lsm[wid][l16] = LV; }                   \
    _Pragma("unroll") for (int dd = 0; dd < 4; ++dd)                           \
      _Pragma("unroll") for (int r = 0; r < 4; ++r)                            \
          Osm[wid][dd][lg * 4 + r][l16] = OV[dd][r];                           \
    __syncthreads();                                                           \
    if (wid == 0) {                                                            \
      float M = Msm[0][l16];                                                   \
      _Pragma("unroll") for (int w = 1; w < 4; ++w) M = fmaxf(M, Msm[w][l16]); \
      float L = 0.0f;                                                          \
      f32x4 oc[4];                                                             \
      _Pragma("unroll") for (int dd = 0; dd < 4; ++dd) oc[dd] = (f32x4)0.0f;   \
      _Pragma("unroll") for (int w = 0; w < 4; ++w) {                          \
        float sc = exp2f(Msm[w][l16] - M);                                     \
        L += Lsm[w][l16] * sc;                                                 \
        _Pragma("unroll") for (int dd = 0; dd < 4; ++dd)                       \
          _Pragma("unroll") for (int r = 0; r < 4; ++r)                        \
              oc[dd][r] += Osm[w][dd][lg * 4 + r][l16] * sc;                   \
      }                                                                        \
      const float inv = 1.0f / L;                                              \
      float* op = out + ((size_t)b * SEQ + (Q0) + l16) * HEAD;                 \
      _Pragma("unroll") for (int dd = 0; dd < 4; ++dd)                         \
        _Pragma("unroll") for (int r = 0; r < 4; ++r)                          \
            op[16 * dd + lg * 4 + r] = oc[dd][r] * inv;                        \
    }                                                                          \
    __syncthreads();                                                           \
  }
  MERGE_PHASE(mA, lA, oA, q0a)
  MERGE_PHASE(mB, lB, oB, q0b)
#undef MERGE_PHASE
}

extern "C" void kernel_launch(void* const* d_in, const int* in_sizes, int n_in,
                              void* d_out, int out_size, void* d_ws, size_t ws_size,
                              hipStream_t stream) {
  (void)in_sizes; (void)n_in; (void)out_size; (void)ws_size;
  const float* x = (const float*)d_in[0];
  const float* W = (const float*)d_in[1];
  float* out = (float*)d_out;

  const size_t MB4 = (size_t)4 * 1024 * 1024;
  unsigned short* Wt = (unsigned short*)d_ws;                               // 384 KB
  unsigned short* PK = (unsigned short*)((char*)d_ws + 512 * 1024);         // 4 MB
  unsigned short* PQ = (unsigned short*)((char*)d_ws + 512 * 1024 + MB4);   // 4 MB
  unsigned short* PV = (unsigned short*)((char*)d_ws + 512 * 1024 + 2 * MB4); // 4 MB

  hipLaunchKernelGGL(wt_kernel, dim3((EMB * N3) / 256), dim3(256), 0, stream, W, Wt);
  hipLaunchKernelGGL(qkv_kernel, dim3((BATCH * SEQ) / BM), dim3(256), 0, stream, x, Wt, PK, PQ, PV);
  hipLaunchKernelGGL(attn_kernel, dim3(BATCH * 128), dim3(256), 0, stream, PK, PQ, PV, out);
}